// Round 5
// baseline (791.458 us; speedup 1.0000x reference)
//
#include <hip/hip_runtime.h>
#include <hip/hip_bf16.h>

// ResidualVQVAE forward, FP32 in / FP32 out.
// R13: revert R12's cooperative launch (NOT graph-capturable in this harness --
// the coop kernel silently never ran). Back to R11 dispatch structure.
// argmin re-tiled for B-reuse: 128 rows/wave (8 row-tiles), 512 rows/block,
// 32 chunks x 256 codes, grid 512 @ launch_bounds(256,2). B-fragment L2 traffic
// drops 4x (512->128 MB/dispatch, L1-shared across the block's 4 waves);
// -h folded into MFMA acc init. Update combines 32 chunks. 19 dispatches.

typedef __bf16 bf16x8 __attribute__((ext_vector_type(8)));
typedef float  f32x4  __attribute__((ext_vector_type(4)));
typedef unsigned short ushort8v __attribute__((ext_vector_type(8)));

#define MFMA16(a,b,c) __builtin_amdgcn_mfma_f32_16x16x32_bf16((a),(b),(c),0,0,0)

__device__ __forceinline__ float b2f(ushort u){ return __uint_as_float(((unsigned)u) << 16); }
__device__ __forceinline__ ushort f2b_rne(float x){
  unsigned u = __float_as_uint(x);
  return (ushort)((u + 0x7fffu + ((u >> 16) & 1u)) >> 16);
}

__device__ __forceinline__ void cvt8(const float* p, bf16x8& h8, bf16x8& l8){
  f32x4 v0 = *(const f32x4*)p;
  f32x4 v1 = *(const f32x4*)(p + 4);
  ushort8v uh, ul;
  #pragma unroll
  for (int i = 0; i < 4; i++){
    float a = v0[i]; ushort h = f2b_rne(a); uh[i] = h;     ul[i]     = f2b_rne(a - b2f(h));
    float b = v1[i]; ushort g = f2b_rne(b); uh[i + 4] = g; ul[i + 4] = f2b_rne(b - b2f(g));
  }
  h8 = __builtin_bit_cast(bf16x8, uh);
  l8 = __builtin_bit_cast(bf16x8, ul);
}

template<int KK, int NN, bool HAS_BLO>
__device__ __forceinline__ f32x4 dotct(const bf16x8* ah, const bf16x8* al,
                                       const ushort* __restrict__ Bfh,
                                       const ushort* __restrict__ Bfl,
                                       int ct, int L){
  constexpr int KS = KK / 32, CT = NN / 16;
  f32x4 acc = {0.f, 0.f, 0.f, 0.f};
  #pragma unroll
  for (int ks = 0; ks < KS; ks++){
    int bo = ((ks * CT + ct) * 64 + L) * 8;
    bf16x8 bh = *(const bf16x8*)(Bfh + bo);
    acc = MFMA16(ah[ks], bh, acc);
    acc = MFMA16(al[ks], bh, acc);
    if constexpr (HAS_BLO){
      bf16x8 bl = *(const bf16x8*)(Bfl + bo);
      acc = MFMA16(ah[ks], bl, acc);
    }
  }
  return acc;
}

// ---------------- prep: weight swizzle + BN fold ------------------------------------------
__device__ __forceinline__ void swz_body(const float* __restrict__ Wm, ushort* __restrict__ Wfh,
                                         ushort* __restrict__ Wfl, int N, int b){
  int gid = b * 256 + threadIdx.x;
  int k = gid / N, n = gid - k * N;
  int kt = k >> 5, kr = k & 31, nt = n >> 4, nr = n & 15;
  int lane = (kr >> 3) * 16 + nr, tt = kr & 7;
  int o = (((kt * (N >> 4)) + nt) * 64 + lane) * 8 + tt;
  float v = Wm[gid];
  ushort h = f2b_rne(v);
  Wfh[o] = h;
  if (Wfl) Wfl[o] = f2b_rne(v - b2f(h));
}

__global__ __launch_bounds__(256) void k_prep(
    const float* __restrict__ W1, const float* __restrict__ W2, const float* __restrict__ W3,
    const float* __restrict__ W4, const float* __restrict__ W5, const float* __restrict__ W6,
    ushort* W1fh, ushort* W1fl, ushort* W2fh, ushort* W2fl, ushort* W3fh, ushort* W3fl,
    ushort* W4fh, ushort* W5fh, ushort* W6fh,
    const float* g1,const float* be1,const float* rm1,const float* rv1,
    const float* g2,const float* be2,const float* rm2,const float* rv2,
    const float* g3,const float* be3,const float* rm3,const float* rv3,
    const float* g4,const float* be4,const float* rm4,const float* rv4,
    float* s1,float* t1,float* s2,float* t2,float* s3,float* t3,float* s4,float* t4)
{
  int b = blockIdx.x;
  if (b < 768){
    if      (b < 128) swz_body(W1, W1fh, W1fl, 128, b);
    else if (b < 256) swz_body(W2, W2fh, W2fl, 256, b - 128);
    else if (b < 384) swz_body(W3, W3fh, W3fl, 128, b - 256);
    else if (b < 512) swz_body(W4, W4fh, nullptr, 256, b - 384);
    else if (b < 640) swz_body(W5, W5fh, nullptr, 128, b - 512);
    else              swz_body(W6, W6fh, nullptr, 256, b - 640);
  } else {
    int t = threadIdx.x;
    if (t < 128){
      float sa = g1[t] / sqrtf(rv1[t] + 1e-5f);
      s1[t] = sa; t1[t] = be1[t] - rm1[t] * sa;
      float sb = g4[t] / sqrtf(rv4[t] + 1e-5f);
      s4[t] = sb; t4[t] = be4[t] - rm4[t] * sb;
    }
    if (t < 256){
      float sa = g2[t] / sqrtf(rv2[t] + 1e-5f);
      s2[t] = sa; t2[t] = be2[t] - rm2[t] * sa;
      float sb = g3[t] / sqrtf(rv3[t] + 1e-5f);
      s3[t] = sb; t3[t] = be3[t] - rm3[t] * sb;
    }
  }
}

// ---------------- fused encoder -----------------------------------------------------------
__global__ __launch_bounds__(256) void k_encoder(
    const float* __restrict__ x,
    const ushort* __restrict__ W1fh, const ushort* __restrict__ W1fl,
    const ushort* __restrict__ W2fh, const ushort* __restrict__ W2fl,
    const ushort* __restrict__ W3fh, const ushort* __restrict__ W3fl,
    const float* __restrict__ b1, const float* __restrict__ s1, const float* __restrict__ t1,
    const float* __restrict__ b2, const float* __restrict__ s2, const float* __restrict__ t2,
    const float* __restrict__ b3,
    ushort* __restrict__ rhi, float* __restrict__ res)
{
  __shared__ __align__(16) float sA[16 * 260];
  __shared__ __align__(16) float sB[16 * 132];
  int tid = threadIdx.x;
  int wv = tid >> 6, L = tid & 63;
  int qd = L >> 4, c16 = L & 15;
  int row0 = blockIdx.x * 16;

  bf16x8 a1h[8], a1l[8];
  #pragma unroll
  for (int ks = 0; ks < 8; ks++)
    cvt8(x + (row0 + c16) * 256 + ks * 32 + qd * 8, a1h[ks], a1l[ks]);

  #pragma unroll
  for (int u = 0; u < 2; u++){
    int ct = wv * 2 + u;
    f32x4 acc = dotct<256,128,true>(a1h, a1l, W1fh, W1fl, ct, L);
    int col = ct * 16 + c16;
    float bia = b1[col], sc = s1[col], sh = t1[col];
    #pragma unroll
    for (int i = 0; i < 4; i++){
      float v = (acc[i] + bia) * sc + sh;
      sB[(qd * 4 + i) * 132 + col] = fmaxf(v, 0.f);
    }
  }
  __syncthreads();

  bf16x8 a2h[4], a2l[4];
  #pragma unroll
  for (int ks = 0; ks < 4; ks++)
    cvt8(sB + c16 * 132 + ks * 32 + qd * 8, a2h[ks], a2l[ks]);

  #pragma unroll
  for (int u = 0; u < 4; u++){
    int ct = wv * 4 + u;
    f32x4 acc = dotct<128,256,true>(a2h, a2l, W2fh, W2fl, ct, L);
    int col = ct * 16 + c16;
    float bia = b2[col], sc = s2[col], sh = t2[col];
    #pragma unroll
    for (int i = 0; i < 4; i++){
      float v = (acc[i] + bia) * sc + sh;
      sA[(qd * 4 + i) * 260 + col] = fmaxf(v, 0.f);
    }
  }
  __syncthreads();

  bf16x8 a3h[8], a3l[8];
  #pragma unroll
  for (int ks = 0; ks < 8; ks++)
    cvt8(sA + c16 * 260 + ks * 32 + qd * 8, a3h[ks], a3l[ks]);

  #pragma unroll
  for (int u = 0; u < 2; u++){
    int ct = wv * 2 + u;
    f32x4 acc = dotct<256,128,true>(a3h, a3l, W3fh, W3fl, ct, L);
    int col = ct * 16 + c16;
    float bia = b3[col];
    #pragma unroll
    for (int i = 0; i < 4; i++){
      int row = row0 + qd * 4 + i;
      float v = acc[i] + bia;
      int o = row * 128 + col;
      res[o] = v;
      rhi[o] = f2b_rne(v);
    }
  }
}

// ---------------- fused decoder -----------------------------------------------------------
__global__ __launch_bounds__(256) void k_decoder(
    const ushort* __restrict__ dhi, const ushort* __restrict__ dlo,
    const ushort* __restrict__ W4fh, const ushort* __restrict__ W5fh,
    const ushort* __restrict__ W6fh,
    const float* __restrict__ b4, const float* __restrict__ s3, const float* __restrict__ t3,
    const float* __restrict__ b5, const float* __restrict__ s4, const float* __restrict__ t4,
    const float* __restrict__ b6,
    float* __restrict__ xhat)
{
  __shared__ __align__(16) float sA[16 * 260];
  __shared__ __align__(16) float sB[16 * 132];
  int tid = threadIdx.x;
  int wv = tid >> 6, L = tid & 63;
  int qd = L >> 4, c16 = L & 15;
  int row0 = blockIdx.x * 16;

  bf16x8 a1h[4], a1l[4];
  #pragma unroll
  for (int ks = 0; ks < 4; ks++){
    int off = (row0 + c16) * 128 + ks * 32 + qd * 8;
    a1h[ks] = *(const bf16x8*)(dhi + off);
    a1l[ks] = *(const bf16x8*)(dlo + off);
  }

  #pragma unroll
  for (int u = 0; u < 4; u++){
    int ct = wv * 4 + u;
    f32x4 acc = dotct<128,256,false>(a1h, a1l, W4fh, nullptr, ct, L);
    int col = ct * 16 + c16;
    float bia = b4[col], sc = s3[col], sh = t3[col];
    #pragma unroll
    for (int i = 0; i < 4; i++){
      float v = (acc[i] + bia) * sc + sh;
      sA[(qd * 4 + i) * 260 + col] = fmaxf(v, 0.f);
    }
  }
  __syncthreads();

  bf16x8 a2h[8], a2l[8];
  #pragma unroll
  for (int ks = 0; ks < 8; ks++)
    cvt8(sA + c16 * 260 + ks * 32 + qd * 8, a2h[ks], a2l[ks]);

  #pragma unroll
  for (int u = 0; u < 2; u++){
    int ct = wv * 2 + u;
    f32x4 acc = dotct<256,128,false>(a2h, a2l, W5fh, nullptr, ct, L);
    int col = ct * 16 + c16;
    float bia = b5[col], sc = s4[col], sh = t4[col];
    #pragma unroll
    for (int i = 0; i < 4; i++){
      float v = (acc[i] + bia) * sc + sh;
      sB[(qd * 4 + i) * 132 + col] = fmaxf(v, 0.f);
    }
  }
  __syncthreads();

  bf16x8 a3h[4], a3l[4];
  #pragma unroll
  for (int ks = 0; ks < 4; ks++)
    cvt8(sB + c16 * 132 + ks * 32 + qd * 8, a3h[ks], a3l[ks]);

  #pragma unroll
  for (int u = 0; u < 4; u++){
    int ct = wv * 4 + u;
    f32x4 acc = dotct<128,256,false>(a3h, a3l, W6fh, nullptr, ct, L);
    int col = ct * 16 + c16;
    float bia = b6[col];
    #pragma unroll
    for (int i = 0; i < 4; i++)
      xhat[(row0 + qd * 4 + i) * 256 + col] = acc[i] + bia;
  }
}

// ---------------- per-book: codebook -> bf16 MFMA B-fragment layout + half-norms ----------
__device__ __forceinline__ void ebook_body(const float* __restrict__ Ef, ushort* __restrict__ Eb,
                                           float* __restrict__ hen, int code, int L){
  float2 e2 = *(const float2*)(Ef + code * 128 + L * 2);
  ushort h0 = f2b_rne(e2.x), h1 = f2b_rne(e2.y);
  int d = L * 2;
  int o = ((((code >> 4) * 4 + (d >> 5)) * 4 + ((d >> 3) & 3)) * 16 + (code & 15)) * 8 + (d & 7);
  *(unsigned*)(Eb + o) = (unsigned)h0 | ((unsigned)h1 << 16);
  float eh0 = b2f(h0), eh1 = b2f(h1);
  float s = eh0 * eh0 + eh1 * eh1;
  #pragma unroll
  for (int mask = 1; mask <= 32; mask <<= 1) s += __shfl_xor(s, mask);
  if (L == 0) hen[code] = 0.5f * s;
}

__global__ __launch_bounds__(256) void k_ebook(const float* __restrict__ Ef,
                                               ushort* __restrict__ Eb, float* __restrict__ hen){
  ebook_body(Ef, Eb, hen, blockIdx.x * 4 + (threadIdx.x >> 6), threadIdx.x & 63);
}

// ---------------- VQ: hi-only argmax(r.e - 0.5||e||^2), 128 rows/wave ---------------------
// grid: 16 row-blocks (512 rows) x 32 chunks (256 codes). Per wave: 8 row-tiles
// resident (64 VGPRs A), 16 code-groups scanned with ping-pong B prefetch; per group
// 32 MFMAs across 8 independent acc chains; acc init = -h. B-fragment traffic is
// amortized over 128 rows (4x less L2 than R11) and L1-shared by the block's 4 waves.
__global__ __launch_bounds__(256, 2) void k_vq_argmin(
  const ushort* __restrict__ Rhi,
  const ushort* __restrict__ Eb, const float* __restrict__ hen,
  float* __restrict__ cq, int* __restrict__ cj)
{
  int rb = blockIdx.x & 15, ch = blockIdx.x >> 4;
  int tid = threadIdx.x;
  int wv = tid >> 6, L = tid & 63;
  int qd = L >> 4, c16 = L & 15;
  int row0 = rb * 512 + wv * 128;

  // resident A fragments: 128 rows, hi only (64 VGPRs)
  bf16x8 ah[8][4];
  #pragma unroll
  for (int t = 0; t < 8; t++){
    int r = row0 + t * 16 + c16;
    #pragma unroll
    for (int ks = 0; ks < 4; ks++)
      ah[t][ks] = *(const bf16x8*)(Rhi + r * 128 + ks * 32 + qd * 8);
  }
  float best[8][4]; int bj[8][4];
  #pragma unroll
  for (int t = 0; t < 8; t++)
    #pragma unroll
    for (int i = 0; i < 4; i++){ best[t][i] = -3.0e38f; bj[t][i] = 0; }

  const ushort* eb = Eb + (size_t)ch * 32768 + L * 8;   // chunk base, frag layout
  const float*  hb = hen + ch * 256 + c16;
  int jb = ch * 256 + c16;

  bf16x8 bA[4], bB[4];
  #pragma unroll
  for (int k = 0; k < 4; k++) bA[k] = *(const bf16x8*)(eb + k * 512);
  #pragma unroll
  for (int k = 0; k < 4; k++) bB[k] = *(const bf16x8*)(eb + 2048 + k * 512);
  float hA = hb[0], hB = hb[16];

  #pragma unroll 1
  for (int g = 0; g < 16; g += 2){
    // ---- group g (bA) ----
    {
      float mh = -hA;
      f32x4 acc[8];
      #pragma unroll
      for (int t = 0; t < 8; t++) acc[t] = (f32x4){mh, mh, mh, mh};
      __builtin_amdgcn_s_setprio(1);
      #pragma unroll
      for (int ks = 0; ks < 4; ks++)
        #pragma unroll
        for (int t = 0; t < 8; t++)
          acc[t] = MFMA16(ah[t][ks], bA[ks], acc[t]);
      __builtin_amdgcn_s_setprio(0);
      int gp = (g + 2 < 16) ? g + 2 : 14;              // clamped (dup harmless)
      const ushort* ebp = eb + gp * 2048;
      #pragma unroll
      for (int k = 0; k < 4; k++) bA[k] = *(const bf16x8*)(ebp + k * 512);
      hA = hb[gp * 16];
      int jc = jb + g * 16;
      #pragma unroll
      for (int t = 0; t < 8; t++)
        #pragma unroll
        for (int i = 0; i < 4; i++)
          if (acc[t][i] > best[t][i]){ best[t][i] = acc[t][i]; bj[t][i] = jc; }
    }
    // ---- group g+1 (bB) ----
    {
      float mh = -hB;
      f32x4 acc[8];
      #pragma unroll
      for (int t = 0; t < 8; t++) acc[t] = (f32x4){mh, mh, mh, mh};
      __builtin_amdgcn_s_setprio(1);
      #pragma unroll
      for (int ks = 0; ks < 4; ks++)
        #pragma unroll
        for (int t = 0; t < 8; t++)
          acc[t] = MFMA16(ah[t][ks], bB[ks], acc[t]);
      __builtin_amdgcn_s_setprio(0);
      int gq = (g + 3 < 16) ? g + 3 : 15;              // clamped
      const ushort* ebq = eb + gq * 2048;
      #pragma unroll
      for (int k = 0; k < 4; k++) bB[k] = *(const bf16x8*)(ebq + k * 512);
      hB = hb[gq * 16];
      int jc = jb + (g + 1) * 16;
      #pragma unroll
      for (int t = 0; t < 8; t++)
        #pragma unroll
        for (int i = 0; i < 4; i++)
          if (acc[t][i] > best[t][i]){ best[t][i] = acc[t][i]; bj[t][i] = jc; }
    }
  }

  // cross-lane reduce over the 16 code-columns, ties -> smaller j
  #pragma unroll
  for (int mask = 1; mask <= 8; mask <<= 1){
    #pragma unroll
    for (int t = 0; t < 8; t++)
      #pragma unroll
      for (int i = 0; i < 4; i++){
        float ob = __shfl_xor(best[t][i], mask);
        int   oj = __shfl_xor(bj[t][i], mask);
        if (ob > best[t][i] || (ob == best[t][i] && oj < bj[t][i])){ best[t][i] = ob; bj[t][i] = oj; }
      }
  }
  if (c16 == 0){
    #pragma unroll
    for (int t = 0; t < 8; t++)
      #pragma unroll
      for (int i = 0; i < 4; i++){
        int r = row0 + t * 16 + qd * 4 + i;
        cq[r * 32 + ch] = best[t][i];
        cj[r * 32 + ch] = bj[t][i];
      }
  }
}

// ---------------- VQ: combine 32 chunk candidates, emit res_s/ce_s, update, + next ebook --
template<bool LAST>
__global__ __launch_bounds__(256) void k_vq_update(
  const float* __restrict__ cq, const int* __restrict__ cj,
  const float* __restrict__ Ef, const float* __restrict__ Efn,
  ushort* __restrict__ Eb, float* __restrict__ hen,
  float* __restrict__ res, const float* __restrict__ ze_s,
  ushort* __restrict__ rhi, ushort* __restrict__ rlo,
  float* __restrict__ res_s, float* __restrict__ ce_s)
{
  int idx = blockIdx.x * 4 + (threadIdx.x >> 6);
  int L = threadIdx.x & 63;
  int c = L & 31;
  float bq = cq[idx * 32 + c]; int bi = cj[idx * 32 + c];
  #pragma unroll
  for (int mask = 1; mask <= 16; mask <<= 1){
    float ob = __shfl_xor(bq, mask);
    int   oj = __shfl_xor(bi, mask);
    if (ob > bq || (ob == bq && oj < bi)){ bq = ob; bi = oj; }
  }
  int o = idx * 128 + L * 2;
  float2 ce = *(const float2*)(Ef + bi * 128 + L * 2);   // fp32 codebook row
  float2 r2 = *(const float2*)(res + o);
  *(float2*)(res_s + o) = r2;
  *(float2*)(ce_s + o) = ce;
  float rn0 = r2.x - ce.x, rn1 = r2.y - ce.y;
  if constexpr (LAST){
    float2 z2 = *(const float2*)(ze_s + o);              // ze from res_s[0]
    float d0 = z2.x - rn0, d1 = z2.y - rn1;              // di = ze - res_final
    ushort h0 = f2b_rne(d0), h1 = f2b_rne(d1);
    *(unsigned*)(rhi + o) = (unsigned)h0 | ((unsigned)h1 << 16);
    ushort l0 = f2b_rne(d0 - b2f(h0)), l1 = f2b_rne(d1 - b2f(h1));
    *(unsigned*)(rlo + o) = (unsigned)l0 | ((unsigned)l1 << 16);
  } else {
    res[o] = rn0; res[o + 1] = rn1;
    ushort h0 = f2b_rne(rn0), h1 = f2b_rne(rn1);
    *(unsigned*)(rhi + o) = (unsigned)h0 | ((unsigned)h1 << 16);
    ebook_body(Efn, Eb, hen, idx, L);
  }
}

extern "C" void kernel_launch(void* const* d_in, const int* in_sizes, int n_in,
                              void* d_out, int out_size, void* d_ws, size_t ws_size,
                              hipStream_t stream)
{
  const float* x   = (const float*)d_in[0];
  const float* W1  = (const float*)d_in[1];
  const float* b1  = (const float*)d_in[2];
  const float* g1  = (const float*)d_in[3];
  const float* be1 = (const float*)d_in[4];
  const float* rm1 = (const float*)d_in[5];
  const float* rv1 = (const float*)d_in[6];
  const float* W2  = (const float*)d_in[7];
  const float* b2  = (const float*)d_in[8];
  const float* g2  = (const float*)d_in[9];
  const float* be2 = (const float*)d_in[10];
  const float* rm2 = (const float*)d_in[11];
  const float* rv2 = (const float*)d_in[12];
  const float* W3  = (const float*)d_in[13];
  const float* b3  = (const float*)d_in[14];
  const float* CB  = (const float*)d_in[15];
  const float* W4  = (const float*)d_in[16];
  const float* b4  = (const float*)d_in[17];
  const float* g3  = (const float*)d_in[18];
  const float* be3 = (const float*)d_in[19];
  const float* rm3 = (const float*)d_in[20];
  const float* rv3 = (const float*)d_in[21];
  const float* W5  = (const float*)d_in[22];
  const float* b5  = (const float*)d_in[23];
  const float* g4  = (const float*)d_in[24];
  const float* be4 = (const float*)d_in[25];
  const float* rm4 = (const float*)d_in[26];
  const float* rv4 = (const float*)d_in[27];
  const float* W6  = (const float*)d_in[28];
  const float* b6  = (const float*)d_in[29];

  char* w = (char*)d_ws;
  ushort* Eb   = (ushort*)(w + 0);             // per-book bf16 codebook (frag layout), 2 MiB
  float*  cq   = (float*) (w + 2097152);       // 8192x32, 1 MiB
  int*    cj   = (int*)   (w + 3145728);       // 8192x32, 1 MiB
  ushort* rhi  = (ushort*)(w + 12582912);      // residual hi split, 2 MiB
  ushort* rlo  = (ushort*)(w + 14680064);      // decoder dlo, 2 MiB
  float*  res  = (float*) (w + 16777216);      // 4 MiB
  float*  hen  = (float*) (w + 25165824);      // per-book half-norms, 32 KiB
  float*  s1   = (float*) (w + 25198592);
  float*  t1   = (float*) (w + 25199104);
  float*  s2   = (float*) (w + 25199616);
  float*  t2   = (float*) (w + 25200640);
  float*  s3   = (float*) (w + 25201664);
  float*  t3   = (float*) (w + 25202688);
  float*  s4   = (float*) (w + 25203712);
  float*  t4   = (float*) (w + 25204224);
  ushort* W1fh = (ushort*)(w + 25204736);
  ushort* W2fh = (ushort*)(w + 25270272);
  ushort* W3fh = (ushort*)(w + 25335808);
  ushort* W4fh = (ushort*)(w + 25401344);
  ushort* W5fh = (ushort*)(w + 25466880);
  ushort* W6fh = (ushort*)(w + 25532416);
  ushort* W1fl = (ushort*)(w + 25597952);
  ushort* W2fl = (ushort*)(w + 25663488);
  ushort* W3fl = (ushort*)(w + 25729024);

  float* xhat  = (float*)d_out;                // [8192,256] fp32
  float* res_s = xhat + 2097152;               // [8,8192,128] fp32
  float* ce_s  = res_s + 8388608;              // [8,8192,128] fp32

  k_prep<<<769, 256, 0, stream>>>(W1, W2, W3, W4, W5, W6,
                                  W1fh, W1fl, W2fh, W2fl, W3fh, W3fl,
                                  W4fh, W5fh, W6fh,
                                  g1,be1,rm1,rv1, g2,be2,rm2,rv2,
                                  g3,be3,rm3,rv3, g4,be4,rm4,rv4,
                                  s1,t1,s2,t2,s3,t3,s4,t4);

  k_encoder<<<512, 256, 0, stream>>>(x, W1fh, W1fl, W2fh, W2fl, W3fh, W3fl,
                                     b1, s1, t1, b2, s2, t2, b3,
                                     rhi, res);

  // residual VQ over 8 books (ebook for book m+1 fused into update(m))
  k_ebook<<<2048, 256, 0, stream>>>(CB, Eb, hen);
  for (int m = 0; m < 8; m++){
    const float* Ef = CB + (size_t)m * 1048576;
    k_vq_argmin<<<512, 256, 0, stream>>>(rhi, Eb, hen, cq, cj);
    if (m < 7){
      k_vq_update<false><<<2048, 256, 0, stream>>>(cq, cj, Ef, Ef + 1048576, Eb, hen,
                                                   res, nullptr, rhi, nullptr,
                                                   res_s + (size_t)m * 1048576,
                                                   ce_s  + (size_t)m * 1048576);
    } else {
      k_vq_update<true><<<2048, 256, 0, stream>>>(cq, cj, Ef, nullptr, Eb, hen,
                                                  res, res_s /*ze = res_s[0]*/, rhi, rlo,
                                                  res_s + (size_t)m * 1048576,
                                                  ce_s  + (size_t)m * 1048576);
    }
  }

  // fused decoder (rhi/rlo hold split(di) from update<LAST>)
  k_decoder<<<512, 256, 0, stream>>>(rhi, rlo, W4fh, W5fh, W6fh,
                                     b4, s3, t3, b5, s4, t4, b6, xhat);
}

// Round 6
// 539.539 us; speedup vs baseline: 1.4669x; 1.4669x over previous
//
#include <hip/hip_runtime.h>
#include <hip/hip_bf16.h>

// ResidualVQVAE forward, FP32 in / FP32 out.
// R14: argmin rebuilt for OCCUPANCY, not in-wave prefetch. R13's counters showed
// spill (VGPR 128 + 137 MB scratch traffic -> 77 us) and R8's showed the real
// regime: latency-bound, MfmaUtil 28% / VALUBusy 26% / Occ 33% at 4 waves/SIMD.
// New argmin: 16 rows/wave, hi-only, single-buffered B, ~59 VGPR @
// launch_bounds(256,8) -> 8 waves/SIMD (32/CU), grid 2048 = 8 blocks/CU.
// TLP hides B-load latency. Scan order identical to R11 -> identical picks.
// Rest of pipeline = R11 (proven 445.8 us / absmax 4.88e-4). 19 dispatches.

typedef __bf16 bf16x8 __attribute__((ext_vector_type(8)));
typedef float  f32x4  __attribute__((ext_vector_type(4)));
typedef unsigned short ushort8v __attribute__((ext_vector_type(8)));

#define MFMA16(a,b,c) __builtin_amdgcn_mfma_f32_16x16x32_bf16((a),(b),(c),0,0,0)

__device__ __forceinline__ float b2f(ushort u){ return __uint_as_float(((unsigned)u) << 16); }
__device__ __forceinline__ ushort f2b_rne(float x){
  unsigned u = __float_as_uint(x);
  return (ushort)((u + 0x7fffu + ((u >> 16) & 1u)) >> 16);
}

__device__ __forceinline__ void cvt8(const float* p, bf16x8& h8, bf16x8& l8){
  f32x4 v0 = *(const f32x4*)p;
  f32x4 v1 = *(const f32x4*)(p + 4);
  ushort8v uh, ul;
  #pragma unroll
  for (int i = 0; i < 4; i++){
    float a = v0[i]; ushort h = f2b_rne(a); uh[i] = h;     ul[i]     = f2b_rne(a - b2f(h));
    float b = v1[i]; ushort g = f2b_rne(b); uh[i + 4] = g; ul[i + 4] = f2b_rne(b - b2f(g));
  }
  h8 = __builtin_bit_cast(bf16x8, uh);
  l8 = __builtin_bit_cast(bf16x8, ul);
}

template<int KK, int NN, bool HAS_BLO>
__device__ __forceinline__ f32x4 dotct(const bf16x8* ah, const bf16x8* al,
                                       const ushort* __restrict__ Bfh,
                                       const ushort* __restrict__ Bfl,
                                       int ct, int L){
  constexpr int KS = KK / 32, CT = NN / 16;
  f32x4 acc = {0.f, 0.f, 0.f, 0.f};
  #pragma unroll
  for (int ks = 0; ks < KS; ks++){
    int bo = ((ks * CT + ct) * 64 + L) * 8;
    bf16x8 bh = *(const bf16x8*)(Bfh + bo);
    acc = MFMA16(ah[ks], bh, acc);
    acc = MFMA16(al[ks], bh, acc);
    if constexpr (HAS_BLO){
      bf16x8 bl = *(const bf16x8*)(Bfl + bo);
      acc = MFMA16(ah[ks], bl, acc);
    }
  }
  return acc;
}

// ---------------- prep: weight swizzle + BN fold ------------------------------------------
__device__ __forceinline__ void swz_body(const float* __restrict__ Wm, ushort* __restrict__ Wfh,
                                         ushort* __restrict__ Wfl, int N, int b){
  int gid = b * 256 + threadIdx.x;
  int k = gid / N, n = gid - k * N;
  int kt = k >> 5, kr = k & 31, nt = n >> 4, nr = n & 15;
  int lane = (kr >> 3) * 16 + nr, tt = kr & 7;
  int o = (((kt * (N >> 4)) + nt) * 64 + lane) * 8 + tt;
  float v = Wm[gid];
  ushort h = f2b_rne(v);
  Wfh[o] = h;
  if (Wfl) Wfl[o] = f2b_rne(v - b2f(h));
}

__global__ __launch_bounds__(256) void k_prep(
    const float* __restrict__ W1, const float* __restrict__ W2, const float* __restrict__ W3,
    const float* __restrict__ W4, const float* __restrict__ W5, const float* __restrict__ W6,
    ushort* W1fh, ushort* W1fl, ushort* W2fh, ushort* W2fl, ushort* W3fh, ushort* W3fl,
    ushort* W4fh, ushort* W5fh, ushort* W6fh,
    const float* g1,const float* be1,const float* rm1,const float* rv1,
    const float* g2,const float* be2,const float* rm2,const float* rv2,
    const float* g3,const float* be3,const float* rm3,const float* rv3,
    const float* g4,const float* be4,const float* rm4,const float* rv4,
    float* s1,float* t1,float* s2,float* t2,float* s3,float* t3,float* s4,float* t4)
{
  int b = blockIdx.x;
  if (b < 768){
    if      (b < 128) swz_body(W1, W1fh, W1fl, 128, b);
    else if (b < 256) swz_body(W2, W2fh, W2fl, 256, b - 128);
    else if (b < 384) swz_body(W3, W3fh, W3fl, 128, b - 256);
    else if (b < 512) swz_body(W4, W4fh, nullptr, 256, b - 384);
    else if (b < 640) swz_body(W5, W5fh, nullptr, 128, b - 512);
    else              swz_body(W6, W6fh, nullptr, 256, b - 640);
  } else {
    int t = threadIdx.x;
    if (t < 128){
      float sa = g1[t] / sqrtf(rv1[t] + 1e-5f);
      s1[t] = sa; t1[t] = be1[t] - rm1[t] * sa;
      float sb = g4[t] / sqrtf(rv4[t] + 1e-5f);
      s4[t] = sb; t4[t] = be4[t] - rm4[t] * sb;
    }
    if (t < 256){
      float sa = g2[t] / sqrtf(rv2[t] + 1e-5f);
      s2[t] = sa; t2[t] = be2[t] - rm2[t] * sa;
      float sb = g3[t] / sqrtf(rv3[t] + 1e-5f);
      s3[t] = sb; t3[t] = be3[t] - rm3[t] * sb;
    }
  }
}

// ---------------- fused encoder -----------------------------------------------------------
__global__ __launch_bounds__(256) void k_encoder(
    const float* __restrict__ x,
    const ushort* __restrict__ W1fh, const ushort* __restrict__ W1fl,
    const ushort* __restrict__ W2fh, const ushort* __restrict__ W2fl,
    const ushort* __restrict__ W3fh, const ushort* __restrict__ W3fl,
    const float* __restrict__ b1, const float* __restrict__ s1, const float* __restrict__ t1,
    const float* __restrict__ b2, const float* __restrict__ s2, const float* __restrict__ t2,
    const float* __restrict__ b3,
    ushort* __restrict__ rhi, float* __restrict__ res)
{
  __shared__ __align__(16) float sA[16 * 260];
  __shared__ __align__(16) float sB[16 * 132];
  int tid = threadIdx.x;
  int wv = tid >> 6, L = tid & 63;
  int qd = L >> 4, c16 = L & 15;
  int row0 = blockIdx.x * 16;

  bf16x8 a1h[8], a1l[8];
  #pragma unroll
  for (int ks = 0; ks < 8; ks++)
    cvt8(x + (row0 + c16) * 256 + ks * 32 + qd * 8, a1h[ks], a1l[ks]);

  #pragma unroll
  for (int u = 0; u < 2; u++){
    int ct = wv * 2 + u;
    f32x4 acc = dotct<256,128,true>(a1h, a1l, W1fh, W1fl, ct, L);
    int col = ct * 16 + c16;
    float bia = b1[col], sc = s1[col], sh = t1[col];
    #pragma unroll
    for (int i = 0; i < 4; i++){
      float v = (acc[i] + bia) * sc + sh;
      sB[(qd * 4 + i) * 132 + col] = fmaxf(v, 0.f);
    }
  }
  __syncthreads();

  bf16x8 a2h[4], a2l[4];
  #pragma unroll
  for (int ks = 0; ks < 4; ks++)
    cvt8(sB + c16 * 132 + ks * 32 + qd * 8, a2h[ks], a2l[ks]);

  #pragma unroll
  for (int u = 0; u < 4; u++){
    int ct = wv * 4 + u;
    f32x4 acc = dotct<128,256,true>(a2h, a2l, W2fh, W2fl, ct, L);
    int col = ct * 16 + c16;
    float bia = b2[col], sc = s2[col], sh = t2[col];
    #pragma unroll
    for (int i = 0; i < 4; i++){
      float v = (acc[i] + bia) * sc + sh;
      sA[(qd * 4 + i) * 260 + col] = fmaxf(v, 0.f);
    }
  }
  __syncthreads();

  bf16x8 a3h[8], a3l[8];
  #pragma unroll
  for (int ks = 0; ks < 8; ks++)
    cvt8(sA + c16 * 260 + ks * 32 + qd * 8, a3h[ks], a3l[ks]);

  #pragma unroll
  for (int u = 0; u < 2; u++){
    int ct = wv * 2 + u;
    f32x4 acc = dotct<256,128,true>(a3h, a3l, W3fh, W3fl, ct, L);
    int col = ct * 16 + c16;
    float bia = b3[col];
    #pragma unroll
    for (int i = 0; i < 4; i++){
      int row = row0 + qd * 4 + i;
      float v = acc[i] + bia;
      int o = row * 128 + col;
      res[o] = v;
      rhi[o] = f2b_rne(v);
    }
  }
}

// ---------------- fused decoder -----------------------------------------------------------
__global__ __launch_bounds__(256) void k_decoder(
    const ushort* __restrict__ dhi, const ushort* __restrict__ dlo,
    const ushort* __restrict__ W4fh, const ushort* __restrict__ W5fh,
    const ushort* __restrict__ W6fh,
    const float* __restrict__ b4, const float* __restrict__ s3, const float* __restrict__ t3,
    const float* __restrict__ b5, const float* __restrict__ s4, const float* __restrict__ t4,
    const float* __restrict__ b6,
    float* __restrict__ xhat)
{
  __shared__ __align__(16) float sA[16 * 260];
  __shared__ __align__(16) float sB[16 * 132];
  int tid = threadIdx.x;
  int wv = tid >> 6, L = tid & 63;
  int qd = L >> 4, c16 = L & 15;
  int row0 = blockIdx.x * 16;

  bf16x8 a1h[4], a1l[4];
  #pragma unroll
  for (int ks = 0; ks < 4; ks++){
    int off = (row0 + c16) * 128 + ks * 32 + qd * 8;
    a1h[ks] = *(const bf16x8*)(dhi + off);
    a1l[ks] = *(const bf16x8*)(dlo + off);
  }

  #pragma unroll
  for (int u = 0; u < 4; u++){
    int ct = wv * 4 + u;
    f32x4 acc = dotct<128,256,false>(a1h, a1l, W4fh, nullptr, ct, L);
    int col = ct * 16 + c16;
    float bia = b4[col], sc = s3[col], sh = t3[col];
    #pragma unroll
    for (int i = 0; i < 4; i++){
      float v = (acc[i] + bia) * sc + sh;
      sA[(qd * 4 + i) * 260 + col] = fmaxf(v, 0.f);
    }
  }
  __syncthreads();

  bf16x8 a2h[8], a2l[8];
  #pragma unroll
  for (int ks = 0; ks < 8; ks++)
    cvt8(sA + c16 * 260 + ks * 32 + qd * 8, a2h[ks], a2l[ks]);

  #pragma unroll
  for (int u = 0; u < 2; u++){
    int ct = wv * 2 + u;
    f32x4 acc = dotct<256,128,false>(a2h, a2l, W5fh, nullptr, ct, L);
    int col = ct * 16 + c16;
    float bia = b5[col], sc = s4[col], sh = t4[col];
    #pragma unroll
    for (int i = 0; i < 4; i++){
      float v = (acc[i] + bia) * sc + sh;
      sB[(qd * 4 + i) * 132 + col] = fmaxf(v, 0.f);
    }
  }
  __syncthreads();

  bf16x8 a3h[4], a3l[4];
  #pragma unroll
  for (int ks = 0; ks < 4; ks++)
    cvt8(sB + c16 * 132 + ks * 32 + qd * 8, a3h[ks], a3l[ks]);

  #pragma unroll
  for (int u = 0; u < 4; u++){
    int ct = wv * 4 + u;
    f32x4 acc = dotct<128,256,false>(a3h, a3l, W6fh, nullptr, ct, L);
    int col = ct * 16 + c16;
    float bia = b6[col];
    #pragma unroll
    for (int i = 0; i < 4; i++)
      xhat[(row0 + qd * 4 + i) * 256 + col] = acc[i] + bia;
  }
}

// ---------------- per-book: codebook -> bf16 MFMA B-fragment layout + half-norms ----------
__device__ __forceinline__ void ebook_body(const float* __restrict__ Ef, ushort* __restrict__ Eb,
                                           float* __restrict__ hen, int code, int L){
  float2 e2 = *(const float2*)(Ef + code * 128 + L * 2);
  ushort h0 = f2b_rne(e2.x), h1 = f2b_rne(e2.y);
  int d = L * 2;
  int o = ((((code >> 4) * 4 + (d >> 5)) * 4 + ((d >> 3) & 3)) * 16 + (code & 15)) * 8 + (d & 7);
  *(unsigned*)(Eb + o) = (unsigned)h0 | ((unsigned)h1 << 16);
  float eh0 = b2f(h0), eh1 = b2f(h1);
  float s = eh0 * eh0 + eh1 * eh1;
  #pragma unroll
  for (int mask = 1; mask <= 32; mask <<= 1) s += __shfl_xor(s, mask);
  if (L == 0) hen[code] = 0.5f * s;
}

__global__ __launch_bounds__(256) void k_ebook(const float* __restrict__ Ef,
                                               ushort* __restrict__ Eb, float* __restrict__ hen){
  ebook_body(Ef, Eb, hen, blockIdx.x * 4 + (threadIdx.x >> 6), threadIdx.x & 63);
}

// ---------------- VQ: hi-only argmax(r.e - 0.5||e||^2), occupancy-first -------------------
// 16 rows/wave, single-buffered B, ~59 VGPR -> 8 waves/SIMD (launch_bounds(256,8)).
// grid: 128 row-blocks (64 rows) x 16 chunks (512 codes) = 2048 = 8 blocks/CU.
// Scan order (32 groups of 16 within chunk) identical to R11 -> identical picks.
__global__ __launch_bounds__(256, 8) void k_vq_argmin(
  const ushort* __restrict__ Rhi,
  const ushort* __restrict__ Eb, const float* __restrict__ hen,
  float* __restrict__ cq, int* __restrict__ cj)
{
  int blk = blockIdx.x;
  int rb = blk & 127, ch = blk >> 7;
  int tid = threadIdx.x;
  int wv = tid >> 6, L = tid & 63;
  int qd = L >> 4, c16 = L & 15;
  int row0 = rb * 64 + wv * 16;

  // resident A: 16 rows hi-only (16 VGPRs)
  bf16x8 ah[4];
  #pragma unroll
  for (int ks = 0; ks < 4; ks++)
    ah[ks] = *(const bf16x8*)(Rhi + (row0 + c16) * 128 + ks * 32 + qd * 8);

  float best[4]; int bj[4];
  #pragma unroll
  for (int i = 0; i < 4; i++){ best[i] = -3.0e38f; bj[i] = 0; }

  const ushort* eb = Eb + (size_t)ch * 65536 + L * 8;   // chunk base, frag layout
  const float*  hb = hen + ch * 512 + c16;
  int jb = ch * 512 + c16;

  #pragma unroll 1
  for (int g = 0; g < 32; ++g){
    const ushort* ebg = eb + g * 2048;
    bf16x8 b0 = *(const bf16x8*)(ebg + 0);
    bf16x8 b1 = *(const bf16x8*)(ebg + 512);
    bf16x8 b2 = *(const bf16x8*)(ebg + 1024);
    bf16x8 b3 = *(const bf16x8*)(ebg + 1536);
    float mh = -hb[g * 16];
    f32x4 acc = {mh, mh, mh, mh};
    acc = MFMA16(ah[0], b0, acc);
    acc = MFMA16(ah[1], b1, acc);
    acc = MFMA16(ah[2], b2, acc);
    acc = MFMA16(ah[3], b3, acc);
    int jc = jb + g * 16;
    #pragma unroll
    for (int i = 0; i < 4; i++)
      if (acc[i] > best[i]){ best[i] = acc[i]; bj[i] = jc; }
  }

  // cross-lane reduce over the 16 code-columns, ties -> smaller j
  #pragma unroll
  for (int mask = 1; mask <= 8; mask <<= 1){
    #pragma unroll
    for (int i = 0; i < 4; i++){
      float ob = __shfl_xor(best[i], mask);
      int   oj = __shfl_xor(bj[i], mask);
      if (ob > best[i] || (ob == best[i] && oj < bj[i])){ best[i] = ob; bj[i] = oj; }
    }
  }
  if (c16 == 0){
    #pragma unroll
    for (int i = 0; i < 4; i++){
      int r = row0 + qd * 4 + i;
      cq[r * 16 + ch] = best[i];
      cj[r * 16 + ch] = bj[i];
    }
  }
}

// ---------------- VQ: combine 16 chunk candidates, emit res_s/ce_s, update, + next ebook --
template<bool LAST>
__global__ __launch_bounds__(256) void k_vq_update(
  const float* __restrict__ cq, const int* __restrict__ cj,
  const float* __restrict__ Ef, const float* __restrict__ Efn,
  ushort* __restrict__ Eb, float* __restrict__ hen,
  float* __restrict__ res, const float* __restrict__ ze_s,
  ushort* __restrict__ rhi, ushort* __restrict__ rlo,
  float* __restrict__ res_s, float* __restrict__ ce_s)
{
  int idx = blockIdx.x * 4 + (threadIdx.x >> 6);
  int L = threadIdx.x & 63;
  int c = L & 15;
  float bq = cq[idx * 16 + c]; int bi = cj[idx * 16 + c];
  #pragma unroll
  for (int mask = 1; mask <= 8; mask <<= 1){
    float ob = __shfl_xor(bq, mask);
    int   oj = __shfl_xor(bi, mask);
    if (ob > bq || (ob == bq && oj < bi)){ bq = ob; bi = oj; }
  }
  int o = idx * 128 + L * 2;
  float2 ce = *(const float2*)(Ef + bi * 128 + L * 2);   // fp32 codebook row
  float2 r2 = *(const float2*)(res + o);
  *(float2*)(res_s + o) = r2;
  *(float2*)(ce_s + o) = ce;
  float rn0 = r2.x - ce.x, rn1 = r2.y - ce.y;
  if constexpr (LAST){
    float2 z2 = *(const float2*)(ze_s + o);              // ze from res_s[0]
    float d0 = z2.x - rn0, d1 = z2.y - rn1;              // di = ze - res_final
    ushort h0 = f2b_rne(d0), h1 = f2b_rne(d1);
    *(unsigned*)(rhi + o) = (unsigned)h0 | ((unsigned)h1 << 16);
    ushort l0 = f2b_rne(d0 - b2f(h0)), l1 = f2b_rne(d1 - b2f(h1));
    *(unsigned*)(rlo + o) = (unsigned)l0 | ((unsigned)l1 << 16);
  } else {
    res[o] = rn0; res[o + 1] = rn1;
    ushort h0 = f2b_rne(rn0), h1 = f2b_rne(rn1);
    *(unsigned*)(rhi + o) = (unsigned)h0 | ((unsigned)h1 << 16);
    ebook_body(Efn, Eb, hen, idx, L);
  }
}

extern "C" void kernel_launch(void* const* d_in, const int* in_sizes, int n_in,
                              void* d_out, int out_size, void* d_ws, size_t ws_size,
                              hipStream_t stream)
{
  const float* x   = (const float*)d_in[0];
  const float* W1  = (const float*)d_in[1];
  const float* b1  = (const float*)d_in[2];
  const float* g1  = (const float*)d_in[3];
  const float* be1 = (const float*)d_in[4];
  const float* rm1 = (const float*)d_in[5];
  const float* rv1 = (const float*)d_in[6];
  const float* W2  = (const float*)d_in[7];
  const float* b2  = (const float*)d_in[8];
  const float* g2  = (const float*)d_in[9];
  const float* be2 = (const float*)d_in[10];
  const float* rm2 = (const float*)d_in[11];
  const float* rv2 = (const float*)d_in[12];
  const float* W3  = (const float*)d_in[13];
  const float* b3  = (const float*)d_in[14];
  const float* CB  = (const float*)d_in[15];
  const float* W4  = (const float*)d_in[16];
  const float* b4  = (const float*)d_in[17];
  const float* g3  = (const float*)d_in[18];
  const float* be3 = (const float*)d_in[19];
  const float* rm3 = (const float*)d_in[20];
  const float* rv3 = (const float*)d_in[21];
  const float* W5  = (const float*)d_in[22];
  const float* b5  = (const float*)d_in[23];
  const float* g4  = (const float*)d_in[24];
  const float* be4 = (const float*)d_in[25];
  const float* rm4 = (const float*)d_in[26];
  const float* rv4 = (const float*)d_in[27];
  const float* W6  = (const float*)d_in[28];
  const float* b6  = (const float*)d_in[29];

  char* w = (char*)d_ws;
  ushort* Eb   = (ushort*)(w + 0);             // per-book bf16 codebook (frag layout), 2 MiB
  float*  cq   = (float*) (w + 2097152);       // 8192x16, 512 KiB
  int*    cj   = (int*)   (w + 2621440);       // 8192x16, 512 KiB
  ushort* rhi  = (ushort*)(w + 12582912);      // residual hi split, 2 MiB
  ushort* rlo  = (ushort*)(w + 14680064);      // decoder dlo, 2 MiB
  float*  res  = (float*) (w + 16777216);      // 4 MiB
  float*  hen  = (float*) (w + 25165824);      // per-book half-norms, 32 KiB
  float*  s1   = (float*) (w + 25198592);
  float*  t1   = (float*) (w + 25199104);
  float*  s2   = (float*) (w + 25199616);
  float*  t2   = (float*) (w + 25200640);
  float*  s3   = (float*) (w + 25201664);
  float*  t3   = (float*) (w + 25202688);
  float*  s4   = (float*) (w + 25203712);
  float*  t4   = (float*) (w + 25204224);
  ushort* W1fh = (ushort*)(w + 25204736);
  ushort* W2fh = (ushort*)(w + 25270272);
  ushort* W3fh = (ushort*)(w + 25335808);
  ushort* W4fh = (ushort*)(w + 25401344);
  ushort* W5fh = (ushort*)(w + 25466880);
  ushort* W6fh = (ushort*)(w + 25532416);
  ushort* W1fl = (ushort*)(w + 25597952);
  ushort* W2fl = (ushort*)(w + 25663488);
  ushort* W3fl = (ushort*)(w + 25729024);

  float* xhat  = (float*)d_out;                // [8192,256] fp32
  float* res_s = xhat + 2097152;               // [8,8192,128] fp32
  float* ce_s  = res_s + 8388608;              // [8,8192,128] fp32

  k_prep<<<769, 256, 0, stream>>>(W1, W2, W3, W4, W5, W6,
                                  W1fh, W1fl, W2fh, W2fl, W3fh, W3fl,
                                  W4fh, W5fh, W6fh,
                                  g1,be1,rm1,rv1, g2,be2,rm2,rv2,
                                  g3,be3,rm3,rv3, g4,be4,rm4,rv4,
                                  s1,t1,s2,t2,s3,t3,s4,t4);

  k_encoder<<<512, 256, 0, stream>>>(x, W1fh, W1fl, W2fh, W2fl, W3fh, W3fl,
                                     b1, s1, t1, b2, s2, t2, b3,
                                     rhi, res);

  // residual VQ over 8 books (ebook for book m+1 fused into update(m))
  k_ebook<<<2048, 256, 0, stream>>>(CB, Eb, hen);
  for (int m = 0; m < 8; m++){
    const float* Ef = CB + (size_t)m * 1048576;
    k_vq_argmin<<<2048, 256, 0, stream>>>(rhi, Eb, hen, cq, cj);
    if (m < 7){
      k_vq_update<false><<<2048, 256, 0, stream>>>(cq, cj, Ef, Ef + 1048576, Eb, hen,
                                                   res, nullptr, rhi, nullptr,
                                                   res_s + (size_t)m * 1048576,
                                                   ce_s  + (size_t)m * 1048576);
    } else {
      k_vq_update<true><<<2048, 256, 0, stream>>>(cq, cj, Ef, nullptr, Eb, hen,
                                                  res, res_s /*ze = res_s[0]*/, rhi, rlo,
                                                  res_s + (size_t)m * 1048576,
                                                  ce_s  + (size_t)m * 1048576);
    }
  }

  // fused decoder (rhi/rlo hold split(di) from update<LAST>)
  k_decoder<<<512, 256, 0, stream>>>(rhi, rlo, W4fh, W5fh, W6fh,
                                     b4, s3, t3, b5, s4, t4, b6, xhat);
}

// Round 7
// 493.951 us; speedup vs baseline: 1.6023x; 1.0923x over previous
//
#include <hip/hip_runtime.h>
#include <hip/hip_bf16.h>

// ResidualVQVAE forward, FP32 in / FP32 out.
// R15: argmin traffic model established (B bytes = 16GB / rows-per-wave; R8/R11/
// R13/R14 all fit). This round: R=64 rows/wave hi-only at a VERIFIED register
// budget (~154 < 170 cap @ launch_bounds(256,3); R13's spill was 260 vs 128).
// 256 rows/block x 32 chunks x 256 codes -> grid 1024, 3 blocks/CU, 12 waves/CU.
// B traffic halves vs R11 (512->256 MB/dispatch). Scan order & tie-breaks
// unchanged -> identical picks. Rest = R11-proven pipeline. 19 dispatches.

typedef __bf16 bf16x8 __attribute__((ext_vector_type(8)));
typedef float  f32x4  __attribute__((ext_vector_type(4)));
typedef unsigned short ushort8v __attribute__((ext_vector_type(8)));

#define MFMA16(a,b,c) __builtin_amdgcn_mfma_f32_16x16x32_bf16((a),(b),(c),0,0,0)

__device__ __forceinline__ float b2f(ushort u){ return __uint_as_float(((unsigned)u) << 16); }
__device__ __forceinline__ ushort f2b_rne(float x){
  unsigned u = __float_as_uint(x);
  return (ushort)((u + 0x7fffu + ((u >> 16) & 1u)) >> 16);
}

__device__ __forceinline__ void cvt8(const float* p, bf16x8& h8, bf16x8& l8){
  f32x4 v0 = *(const f32x4*)p;
  f32x4 v1 = *(const f32x4*)(p + 4);
  ushort8v uh, ul;
  #pragma unroll
  for (int i = 0; i < 4; i++){
    float a = v0[i]; ushort h = f2b_rne(a); uh[i] = h;     ul[i]     = f2b_rne(a - b2f(h));
    float b = v1[i]; ushort g = f2b_rne(b); uh[i + 4] = g; ul[i + 4] = f2b_rne(b - b2f(g));
  }
  h8 = __builtin_bit_cast(bf16x8, uh);
  l8 = __builtin_bit_cast(bf16x8, ul);
}

template<int KK, int NN, bool HAS_BLO>
__device__ __forceinline__ f32x4 dotct(const bf16x8* ah, const bf16x8* al,
                                       const ushort* __restrict__ Bfh,
                                       const ushort* __restrict__ Bfl,
                                       int ct, int L){
  constexpr int KS = KK / 32, CT = NN / 16;
  f32x4 acc = {0.f, 0.f, 0.f, 0.f};
  #pragma unroll
  for (int ks = 0; ks < KS; ks++){
    int bo = ((ks * CT + ct) * 64 + L) * 8;
    bf16x8 bh = *(const bf16x8*)(Bfh + bo);
    acc = MFMA16(ah[ks], bh, acc);
    acc = MFMA16(al[ks], bh, acc);
    if constexpr (HAS_BLO){
      bf16x8 bl = *(const bf16x8*)(Bfl + bo);
      acc = MFMA16(ah[ks], bl, acc);
    }
  }
  return acc;
}

// ---------------- prep: weight swizzle + BN fold ------------------------------------------
__device__ __forceinline__ void swz_body(const float* __restrict__ Wm, ushort* __restrict__ Wfh,
                                         ushort* __restrict__ Wfl, int N, int b){
  int gid = b * 256 + threadIdx.x;
  int k = gid / N, n = gid - k * N;
  int kt = k >> 5, kr = k & 31, nt = n >> 4, nr = n & 15;
  int lane = (kr >> 3) * 16 + nr, tt = kr & 7;
  int o = (((kt * (N >> 4)) + nt) * 64 + lane) * 8 + tt;
  float v = Wm[gid];
  ushort h = f2b_rne(v);
  Wfh[o] = h;
  if (Wfl) Wfl[o] = f2b_rne(v - b2f(h));
}

__global__ __launch_bounds__(256) void k_prep(
    const float* __restrict__ W1, const float* __restrict__ W2, const float* __restrict__ W3,
    const float* __restrict__ W4, const float* __restrict__ W5, const float* __restrict__ W6,
    ushort* W1fh, ushort* W1fl, ushort* W2fh, ushort* W2fl, ushort* W3fh, ushort* W3fl,
    ushort* W4fh, ushort* W5fh, ushort* W6fh,
    const float* g1,const float* be1,const float* rm1,const float* rv1,
    const float* g2,const float* be2,const float* rm2,const float* rv2,
    const float* g3,const float* be3,const float* rm3,const float* rv3,
    const float* g4,const float* be4,const float* rm4,const float* rv4,
    float* s1,float* t1,float* s2,float* t2,float* s3,float* t3,float* s4,float* t4)
{
  int b = blockIdx.x;
  if (b < 768){
    if      (b < 128) swz_body(W1, W1fh, W1fl, 128, b);
    else if (b < 256) swz_body(W2, W2fh, W2fl, 256, b - 128);
    else if (b < 384) swz_body(W3, W3fh, W3fl, 128, b - 256);
    else if (b < 512) swz_body(W4, W4fh, nullptr, 256, b - 384);
    else if (b < 640) swz_body(W5, W5fh, nullptr, 128, b - 512);
    else              swz_body(W6, W6fh, nullptr, 256, b - 640);
  } else {
    int t = threadIdx.x;
    if (t < 128){
      float sa = g1[t] / sqrtf(rv1[t] + 1e-5f);
      s1[t] = sa; t1[t] = be1[t] - rm1[t] * sa;
      float sb = g4[t] / sqrtf(rv4[t] + 1e-5f);
      s4[t] = sb; t4[t] = be4[t] - rm4[t] * sb;
    }
    if (t < 256){
      float sa = g2[t] / sqrtf(rv2[t] + 1e-5f);
      s2[t] = sa; t2[t] = be2[t] - rm2[t] * sa;
      float sb = g3[t] / sqrtf(rv3[t] + 1e-5f);
      s3[t] = sb; t3[t] = be3[t] - rm3[t] * sb;
    }
  }
}

// ---------------- fused encoder -----------------------------------------------------------
__global__ __launch_bounds__(256) void k_encoder(
    const float* __restrict__ x,
    const ushort* __restrict__ W1fh, const ushort* __restrict__ W1fl,
    const ushort* __restrict__ W2fh, const ushort* __restrict__ W2fl,
    const ushort* __restrict__ W3fh, const ushort* __restrict__ W3fl,
    const float* __restrict__ b1, const float* __restrict__ s1, const float* __restrict__ t1,
    const float* __restrict__ b2, const float* __restrict__ s2, const float* __restrict__ t2,
    const float* __restrict__ b3,
    ushort* __restrict__ rhi, float* __restrict__ res)
{
  __shared__ __align__(16) float sA[16 * 260];
  __shared__ __align__(16) float sB[16 * 132];
  int tid = threadIdx.x;
  int wv = tid >> 6, L = tid & 63;
  int qd = L >> 4, c16 = L & 15;
  int row0 = blockIdx.x * 16;

  bf16x8 a1h[8], a1l[8];
  #pragma unroll
  for (int ks = 0; ks < 8; ks++)
    cvt8(x + (row0 + c16) * 256 + ks * 32 + qd * 8, a1h[ks], a1l[ks]);

  #pragma unroll
  for (int u = 0; u < 2; u++){
    int ct = wv * 2 + u;
    f32x4 acc = dotct<256,128,true>(a1h, a1l, W1fh, W1fl, ct, L);
    int col = ct * 16 + c16;
    float bia = b1[col], sc = s1[col], sh = t1[col];
    #pragma unroll
    for (int i = 0; i < 4; i++){
      float v = (acc[i] + bia) * sc + sh;
      sB[(qd * 4 + i) * 132 + col] = fmaxf(v, 0.f);
    }
  }
  __syncthreads();

  bf16x8 a2h[4], a2l[4];
  #pragma unroll
  for (int ks = 0; ks < 4; ks++)
    cvt8(sB + c16 * 132 + ks * 32 + qd * 8, a2h[ks], a2l[ks]);

  #pragma unroll
  for (int u = 0; u < 4; u++){
    int ct = wv * 4 + u;
    f32x4 acc = dotct<128,256,true>(a2h, a2l, W2fh, W2fl, ct, L);
    int col = ct * 16 + c16;
    float bia = b2[col], sc = s2[col], sh = t2[col];
    #pragma unroll
    for (int i = 0; i < 4; i++){
      float v = (acc[i] + bia) * sc + sh;
      sA[(qd * 4 + i) * 260 + col] = fmaxf(v, 0.f);
    }
  }
  __syncthreads();

  bf16x8 a3h[8], a3l[8];
  #pragma unroll
  for (int ks = 0; ks < 8; ks++)
    cvt8(sA + c16 * 260 + ks * 32 + qd * 8, a3h[ks], a3l[ks]);

  #pragma unroll
  for (int u = 0; u < 2; u++){
    int ct = wv * 2 + u;
    f32x4 acc = dotct<256,128,true>(a3h, a3l, W3fh, W3fl, ct, L);
    int col = ct * 16 + c16;
    float bia = b3[col];
    #pragma unroll
    for (int i = 0; i < 4; i++){
      int row = row0 + qd * 4 + i;
      float v = acc[i] + bia;
      int o = row * 128 + col;
      res[o] = v;
      rhi[o] = f2b_rne(v);
    }
  }
}

// ---------------- fused decoder -----------------------------------------------------------
__global__ __launch_bounds__(256) void k_decoder(
    const ushort* __restrict__ dhi, const ushort* __restrict__ dlo,
    const ushort* __restrict__ W4fh, const ushort* __restrict__ W5fh,
    const ushort* __restrict__ W6fh,
    const float* __restrict__ b4, const float* __restrict__ s3, const float* __restrict__ t3,
    const float* __restrict__ b5, const float* __restrict__ s4, const float* __restrict__ t4,
    const float* __restrict__ b6,
    float* __restrict__ xhat)
{
  __shared__ __align__(16) float sA[16 * 260];
  __shared__ __align__(16) float sB[16 * 132];
  int tid = threadIdx.x;
  int wv = tid >> 6, L = tid & 63;
  int qd = L >> 4, c16 = L & 15;
  int row0 = blockIdx.x * 16;

  bf16x8 a1h[4], a1l[4];
  #pragma unroll
  for (int ks = 0; ks < 4; ks++){
    int off = (row0 + c16) * 128 + ks * 32 + qd * 8;
    a1h[ks] = *(const bf16x8*)(dhi + off);
    a1l[ks] = *(const bf16x8*)(dlo + off);
  }

  #pragma unroll
  for (int u = 0; u < 4; u++){
    int ct = wv * 4 + u;
    f32x4 acc = dotct<128,256,false>(a1h, a1l, W4fh, nullptr, ct, L);
    int col = ct * 16 + c16;
    float bia = b4[col], sc = s3[col], sh = t3[col];
    #pragma unroll
    for (int i = 0; i < 4; i++){
      float v = (acc[i] + bia) * sc + sh;
      sA[(qd * 4 + i) * 260 + col] = fmaxf(v, 0.f);
    }
  }
  __syncthreads();

  bf16x8 a2h[8], a2l[8];
  #pragma unroll
  for (int ks = 0; ks < 8; ks++)
    cvt8(sA + c16 * 260 + ks * 32 + qd * 8, a2h[ks], a2l[ks]);

  #pragma unroll
  for (int u = 0; u < 2; u++){
    int ct = wv * 2 + u;
    f32x4 acc = dotct<256,128,false>(a2h, a2l, W5fh, nullptr, ct, L);
    int col = ct * 16 + c16;
    float bia = b5[col], sc = s4[col], sh = t4[col];
    #pragma unroll
    for (int i = 0; i < 4; i++){
      float v = (acc[i] + bia) * sc + sh;
      sB[(qd * 4 + i) * 132 + col] = fmaxf(v, 0.f);
    }
  }
  __syncthreads();

  bf16x8 a3h[4], a3l[4];
  #pragma unroll
  for (int ks = 0; ks < 4; ks++)
    cvt8(sB + c16 * 132 + ks * 32 + qd * 8, a3h[ks], a3l[ks]);

  #pragma unroll
  for (int u = 0; u < 4; u++){
    int ct = wv * 4 + u;
    f32x4 acc = dotct<128,256,false>(a3h, a3l, W6fh, nullptr, ct, L);
    int col = ct * 16 + c16;
    float bia = b6[col];
    #pragma unroll
    for (int i = 0; i < 4; i++)
      xhat[(row0 + qd * 4 + i) * 256 + col] = acc[i] + bia;
  }
}

// ---------------- per-book: codebook -> bf16 MFMA B-fragment layout + half-norms ----------
__device__ __forceinline__ void ebook_body(const float* __restrict__ Ef, ushort* __restrict__ Eb,
                                           float* __restrict__ hen, int code, int L){
  float2 e2 = *(const float2*)(Ef + code * 128 + L * 2);
  ushort h0 = f2b_rne(e2.x), h1 = f2b_rne(e2.y);
  int d = L * 2;
  int o = ((((code >> 4) * 4 + (d >> 5)) * 4 + ((d >> 3) & 3)) * 16 + (code & 15)) * 8 + (d & 7);
  *(unsigned*)(Eb + o) = (unsigned)h0 | ((unsigned)h1 << 16);
  float eh0 = b2f(h0), eh1 = b2f(h1);
  float s = eh0 * eh0 + eh1 * eh1;
  #pragma unroll
  for (int mask = 1; mask <= 32; mask <<= 1) s += __shfl_xor(s, mask);
  if (L == 0) hen[code] = 0.5f * s;
}

__global__ __launch_bounds__(256) void k_ebook(const float* __restrict__ Ef,
                                               ushort* __restrict__ Eb, float* __restrict__ hen){
  ebook_body(Ef, Eb, hen, blockIdx.x * 4 + (threadIdx.x >> 6), threadIdx.x & 63);
}

// ---------------- VQ: hi-only argmax(r.e - 0.5||e||^2), 64 rows/wave ----------------------
// grid: 32 row-blocks (256 rows) x 32 chunks (256 codes) = 1024. 4 waves/block,
// 64 rows/wave: ah[4][4]=64 + best/bj=32 + bA/bB=32 + acc=16 + misc ~10 = ~154 VGPR
// @ launch_bounds(256,3) cap ~170 -> NO spill, 3 blocks/CU (12 waves/CU).
// B traffic = 16GB/R = 256 MB/dispatch (half of R11). 2-deep ping-pong prefetch;
// -h folded into acc init. Scan order identical -> identical picks.
__global__ __launch_bounds__(256, 3) void k_vq_argmin(
  const ushort* __restrict__ Rhi,
  const ushort* __restrict__ Eb, const float* __restrict__ hen,
  float* __restrict__ cq, int* __restrict__ cj)
{
  int rb = blockIdx.x & 31, ch = blockIdx.x >> 5;
  int tid = threadIdx.x;
  int wv = tid >> 6, L = tid & 63;
  int qd = L >> 4, c16 = L & 15;
  int row0 = rb * 256 + wv * 64;

  // resident A: 64 rows hi-only (64 VGPRs)
  bf16x8 ah[4][4];
  #pragma unroll
  for (int t = 0; t < 4; t++){
    int r = row0 + t * 16 + c16;
    #pragma unroll
    for (int ks = 0; ks < 4; ks++)
      ah[t][ks] = *(const bf16x8*)(Rhi + r * 128 + ks * 32 + qd * 8);
  }
  float best[4][4]; int bj[4][4];
  #pragma unroll
  for (int t = 0; t < 4; t++)
    #pragma unroll
    for (int i = 0; i < 4; i++){ best[t][i] = -3.0e38f; bj[t][i] = 0; }

  const ushort* eb = Eb + (size_t)ch * 32768 + L * 8;   // chunk: 256 codes x 128 dims
  const float*  hb = hen + ch * 256 + c16;
  int jb = ch * 256 + c16;

  // 2-group-deep ping-pong
  bf16x8 bA[4], bB[4];
  #pragma unroll
  for (int k = 0; k < 4; k++) bA[k] = *(const bf16x8*)(eb + k * 512);
  #pragma unroll
  for (int k = 0; k < 4; k++) bB[k] = *(const bf16x8*)(eb + 2048 + k * 512);
  float hA = hb[0], hB = hb[16];

  #pragma unroll 1
  for (int g = 0; g < 16; g += 2){
    // ---- group g (bA) ----
    {
      float mh = -hA;
      f32x4 a0 = {mh,mh,mh,mh}, a1 = {mh,mh,mh,mh}, a2 = {mh,mh,mh,mh}, a3 = {mh,mh,mh,mh};
      __builtin_amdgcn_s_setprio(1);
      a0 = MFMA16(ah[0][0], bA[0], a0); a1 = MFMA16(ah[1][0], bA[0], a1);
      a2 = MFMA16(ah[2][0], bA[0], a2); a3 = MFMA16(ah[3][0], bA[0], a3);
      a0 = MFMA16(ah[0][1], bA[1], a0); a1 = MFMA16(ah[1][1], bA[1], a1);
      a2 = MFMA16(ah[2][1], bA[1], a2); a3 = MFMA16(ah[3][1], bA[1], a3);
      a0 = MFMA16(ah[0][2], bA[2], a0); a1 = MFMA16(ah[1][2], bA[2], a1);
      a2 = MFMA16(ah[2][2], bA[2], a2); a3 = MFMA16(ah[3][2], bA[2], a3);
      a0 = MFMA16(ah[0][3], bA[3], a0); a1 = MFMA16(ah[1][3], bA[3], a1);
      a2 = MFMA16(ah[2][3], bA[3], a2); a3 = MFMA16(ah[3][3], bA[3], a3);
      __builtin_amdgcn_s_setprio(0);
      // prefetch group g+2 into bA (clamped; duplicate harmless)
      int gp = (g + 2 < 16) ? g + 2 : 14;
      const ushort* ebp = eb + gp * 2048;
      #pragma unroll
      for (int k = 0; k < 4; k++) bA[k] = *(const bf16x8*)(ebp + k * 512);
      hA = hb[gp * 16];
      int jc = jb + g * 16;
      #pragma unroll
      for (int i = 0; i < 4; i++){
        if (a0[i] > best[0][i]){ best[0][i] = a0[i]; bj[0][i] = jc; }
        if (a1[i] > best[1][i]){ best[1][i] = a1[i]; bj[1][i] = jc; }
        if (a2[i] > best[2][i]){ best[2][i] = a2[i]; bj[2][i] = jc; }
        if (a3[i] > best[3][i]){ best[3][i] = a3[i]; bj[3][i] = jc; }
      }
    }
    // ---- group g+1 (bB) ----
    {
      float mh = -hB;
      f32x4 a0 = {mh,mh,mh,mh}, a1 = {mh,mh,mh,mh}, a2 = {mh,mh,mh,mh}, a3 = {mh,mh,mh,mh};
      __builtin_amdgcn_s_setprio(1);
      a0 = MFMA16(ah[0][0], bB[0], a0); a1 = MFMA16(ah[1][0], bB[0], a1);
      a2 = MFMA16(ah[2][0], bB[0], a2); a3 = MFMA16(ah[3][0], bB[0], a3);
      a0 = MFMA16(ah[0][1], bB[1], a0); a1 = MFMA16(ah[1][1], bB[1], a1);
      a2 = MFMA16(ah[2][1], bB[1], a2); a3 = MFMA16(ah[3][1], bB[1], a3);
      a0 = MFMA16(ah[0][2], bB[2], a0); a1 = MFMA16(ah[1][2], bB[2], a1);
      a2 = MFMA16(ah[2][2], bB[2], a2); a3 = MFMA16(ah[3][2], bB[2], a3);
      a0 = MFMA16(ah[0][3], bB[3], a0); a1 = MFMA16(ah[1][3], bB[3], a1);
      a2 = MFMA16(ah[2][3], bB[3], a2); a3 = MFMA16(ah[3][3], bB[3], a3);
      __builtin_amdgcn_s_setprio(0);
      // prefetch group g+3 into bB (clamped)
      int gq = (g + 3 < 16) ? g + 3 : 15;
      const ushort* ebq = eb + gq * 2048;
      #pragma unroll
      for (int k = 0; k < 4; k++) bB[k] = *(const bf16x8*)(ebq + k * 512);
      hB = hb[gq * 16];
      int jc = jb + (g + 1) * 16;
      #pragma unroll
      for (int i = 0; i < 4; i++){
        if (a0[i] > best[0][i]){ best[0][i] = a0[i]; bj[0][i] = jc; }
        if (a1[i] > best[1][i]){ best[1][i] = a1[i]; bj[1][i] = jc; }
        if (a2[i] > best[2][i]){ best[2][i] = a2[i]; bj[2][i] = jc; }
        if (a3[i] > best[3][i]){ best[3][i] = a3[i]; bj[3][i] = jc; }
      }
    }
  }

  // cross-lane reduce over the 16 code-columns, ties -> smaller j
  #pragma unroll
  for (int mask = 1; mask <= 8; mask <<= 1){
    #pragma unroll
    for (int t = 0; t < 4; t++)
      #pragma unroll
      for (int i = 0; i < 4; i++){
        float ob = __shfl_xor(best[t][i], mask);
        int   oj = __shfl_xor(bj[t][i], mask);
        if (ob > best[t][i] || (ob == best[t][i] && oj < bj[t][i])){ best[t][i] = ob; bj[t][i] = oj; }
      }
  }
  if (c16 == 0){
    #pragma unroll
    for (int t = 0; t < 4; t++)
      #pragma unroll
      for (int i = 0; i < 4; i++){
        int r = row0 + t * 16 + qd * 4 + i;
        cq[r * 32 + ch] = best[t][i];
        cj[r * 32 + ch] = bj[t][i];
      }
  }
}

// ---------------- VQ: combine 32 chunk candidates, emit res_s/ce_s, update, + next ebook --
template<bool LAST>
__global__ __launch_bounds__(256) void k_vq_update(
  const float* __restrict__ cq, const int* __restrict__ cj,
  const float* __restrict__ Ef, const float* __restrict__ Efn,
  ushort* __restrict__ Eb, float* __restrict__ hen,
  float* __restrict__ res, const float* __restrict__ ze_s,
  ushort* __restrict__ rhi, ushort* __restrict__ rlo,
  float* __restrict__ res_s, float* __restrict__ ce_s)
{
  int idx = blockIdx.x * 4 + (threadIdx.x >> 6);
  int L = threadIdx.x & 63;
  int c = L & 31;
  float bq = cq[idx * 32 + c]; int bi = cj[idx * 32 + c];
  #pragma unroll
  for (int mask = 1; mask <= 16; mask <<= 1){
    float ob = __shfl_xor(bq, mask);
    int   oj = __shfl_xor(bi, mask);
    if (ob > bq || (ob == bq && oj < bi)){ bq = ob; bi = oj; }
  }
  int o = idx * 128 + L * 2;
  float2 ce = *(const float2*)(Ef + bi * 128 + L * 2);   // fp32 codebook row
  float2 r2 = *(const float2*)(res + o);
  *(float2*)(res_s + o) = r2;
  *(float2*)(ce_s + o) = ce;
  float rn0 = r2.x - ce.x, rn1 = r2.y - ce.y;
  if constexpr (LAST){
    float2 z2 = *(const float2*)(ze_s + o);              // ze from res_s[0]
    float d0 = z2.x - rn0, d1 = z2.y - rn1;              // di = ze - res_final
    ushort h0 = f2b_rne(d0), h1 = f2b_rne(d1);
    *(unsigned*)(rhi + o) = (unsigned)h0 | ((unsigned)h1 << 16);
    ushort l0 = f2b_rne(d0 - b2f(h0)), l1 = f2b_rne(d1 - b2f(h1));
    *(unsigned*)(rlo + o) = (unsigned)l0 | ((unsigned)l1 << 16);
  } else {
    res[o] = rn0; res[o + 1] = rn1;
    ushort h0 = f2b_rne(rn0), h1 = f2b_rne(rn1);
    *(unsigned*)(rhi + o) = (unsigned)h0 | ((unsigned)h1 << 16);
    ebook_body(Efn, Eb, hen, idx, L);
  }
}

extern "C" void kernel_launch(void* const* d_in, const int* in_sizes, int n_in,
                              void* d_out, int out_size, void* d_ws, size_t ws_size,
                              hipStream_t stream)
{
  const float* x   = (const float*)d_in[0];
  const float* W1  = (const float*)d_in[1];
  const float* b1  = (const float*)d_in[2];
  const float* g1  = (const float*)d_in[3];
  const float* be1 = (const float*)d_in[4];
  const float* rm1 = (const float*)d_in[5];
  const float* rv1 = (const float*)d_in[6];
  const float* W2  = (const float*)d_in[7];
  const float* b2  = (const float*)d_in[8];
  const float* g2  = (const float*)d_in[9];
  const float* be2 = (const float*)d_in[10];
  const float* rm2 = (const float*)d_in[11];
  const float* rv2 = (const float*)d_in[12];
  const float* W3  = (const float*)d_in[13];
  const float* b3  = (const float*)d_in[14];
  const float* CB  = (const float*)d_in[15];
  const float* W4  = (const float*)d_in[16];
  const float* b4  = (const float*)d_in[17];
  const float* g3  = (const float*)d_in[18];
  const float* be3 = (const float*)d_in[19];
  const float* rm3 = (const float*)d_in[20];
  const float* rv3 = (const float*)d_in[21];
  const float* W5  = (const float*)d_in[22];
  const float* b5  = (const float*)d_in[23];
  const float* g4  = (const float*)d_in[24];
  const float* be4 = (const float*)d_in[25];
  const float* rm4 = (const float*)d_in[26];
  const float* rv4 = (const float*)d_in[27];
  const float* W6  = (const float*)d_in[28];
  const float* b6  = (const float*)d_in[29];

  char* w = (char*)d_ws;
  ushort* Eb   = (ushort*)(w + 0);             // per-book bf16 codebook (frag layout), 2 MiB
  float*  cq   = (float*) (w + 2097152);       // 8192x32, 1 MiB
  int*    cj   = (int*)   (w + 3145728);       // 8192x32, 1 MiB
  ushort* rhi  = (ushort*)(w + 12582912);      // residual hi split, 2 MiB
  ushort* rlo  = (ushort*)(w + 14680064);      // decoder dlo, 2 MiB
  float*  res  = (float*) (w + 16777216);      // 4 MiB
  float*  hen  = (float*) (w + 25165824);      // per-book half-norms, 32 KiB
  float*  s1   = (float*) (w + 25198592);
  float*  t1   = (float*) (w + 25199104);
  float*  s2   = (float*) (w + 25199616);
  float*  t2   = (float*) (w + 25200640);
  float*  s3   = (float*) (w + 25201664);
  float*  t3   = (float*) (w + 25202688);
  float*  s4   = (float*) (w + 25203712);
  float*  t4   = (float*) (w + 25204224);
  ushort* W1fh = (ushort*)(w + 25204736);
  ushort* W2fh = (ushort*)(w + 25270272);
  ushort* W3fh = (ushort*)(w + 25335808);
  ushort* W4fh = (ushort*)(w + 25401344);
  ushort* W5fh = (ushort*)(w + 25466880);
  ushort* W6fh = (ushort*)(w + 25532416);
  ushort* W1fl = (ushort*)(w + 25597952);
  ushort* W2fl = (ushort*)(w + 25663488);
  ushort* W3fl = (ushort*)(w + 25729024);

  float* xhat  = (float*)d_out;                // [8192,256] fp32
  float* res_s = xhat + 2097152;               // [8,8192,128] fp32
  float* ce_s  = res_s + 8388608;              // [8,8192,128] fp32

  k_prep<<<769, 256, 0, stream>>>(W1, W2, W3, W4, W5, W6,
                                  W1fh, W1fl, W2fh, W2fl, W3fh, W3fl,
                                  W4fh, W5fh, W6fh,
                                  g1,be1,rm1,rv1, g2,be2,rm2,rv2,
                                  g3,be3,rm3,rv3, g4,be4,rm4,rv4,
                                  s1,t1,s2,t2,s3,t3,s4,t4);

  k_encoder<<<512, 256, 0, stream>>>(x, W1fh, W1fl, W2fh, W2fl, W3fh, W3fl,
                                     b1, s1, t1, b2, s2, t2, b3,
                                     rhi, res);

  // residual VQ over 8 books (ebook for book m+1 fused into update(m))
  k_ebook<<<2048, 256, 0, stream>>>(CB, Eb, hen);
  for (int m = 0; m < 8; m++){
    const float* Ef = CB + (size_t)m * 1048576;
    k_vq_argmin<<<1024, 256, 0, stream>>>(rhi, Eb, hen, cq, cj);
    if (m < 7){
      k_vq_update<false><<<2048, 256, 0, stream>>>(cq, cj, Ef, Ef + 1048576, Eb, hen,
                                                   res, nullptr, rhi, nullptr,
                                                   res_s + (size_t)m * 1048576,
                                                   ce_s  + (size_t)m * 1048576);
    } else {
      k_vq_update<true><<<2048, 256, 0, stream>>>(cq, cj, Ef, nullptr, Eb, hen,
                                                  res, res_s /*ze = res_s[0]*/, rhi, rlo,
                                                  res_s + (size_t)m * 1048576,
                                                  ce_s  + (size_t)m * 1048576);
    }
  }

  // fused decoder (rhi/rlo hold split(di) from update<LAST>)
  k_decoder<<<512, 256, 0, stream>>>(rhi, rlo, W4fh, W5fh, W6fh,
                                     b4, s3, t3, b5, s4, t4, b6, xhat);
}

// Round 8
// 416.725 us; speedup vs baseline: 1.8992x; 1.1853x over previous
//
#include <hip/hip_runtime.h>
#include <hip/hip_bf16.h>

// ResidualVQVAE forward, FP32 in / FP32 out.
// R16: argmin = R8's LDS-staged skeleton + all proven wins. R=32/wave (the measured
// optimum of the register-blocking family: R=16 doubles traffic, R>=64 hits the VGPR
// wall), hi-only, -h acc-init fold, and T14 async-STAGE: issue next-tile global loads
// -> compute current tile from LDS -> write staged regs -> ONE barrier/tile. Global B
// traffic 512->128 MB/dispatch (one stage per block, not per wave); HBM/L2 latency
// hides under compute. Scan order/tie-breaks/geometry identical to R11 -> identical
// picks. ebook0 folded into k_prep. 18 dispatches.

typedef __bf16 bf16x8 __attribute__((ext_vector_type(8)));
typedef float  f32x4  __attribute__((ext_vector_type(4)));
typedef unsigned short ushort8v __attribute__((ext_vector_type(8)));

#define MFMA16(a,b,c) __builtin_amdgcn_mfma_f32_16x16x32_bf16((a),(b),(c),0,0,0)

__device__ __forceinline__ float b2f(ushort u){ return __uint_as_float(((unsigned)u) << 16); }
__device__ __forceinline__ ushort f2b_rne(float x){
  unsigned u = __float_as_uint(x);
  return (ushort)((u + 0x7fffu + ((u >> 16) & 1u)) >> 16);
}

__device__ __forceinline__ void cvt8(const float* p, bf16x8& h8, bf16x8& l8){
  f32x4 v0 = *(const f32x4*)p;
  f32x4 v1 = *(const f32x4*)(p + 4);
  ushort8v uh, ul;
  #pragma unroll
  for (int i = 0; i < 4; i++){
    float a = v0[i]; ushort h = f2b_rne(a); uh[i] = h;     ul[i]     = f2b_rne(a - b2f(h));
    float b = v1[i]; ushort g = f2b_rne(b); uh[i + 4] = g; ul[i + 4] = f2b_rne(b - b2f(g));
  }
  h8 = __builtin_bit_cast(bf16x8, uh);
  l8 = __builtin_bit_cast(bf16x8, ul);
}

template<int KK, int NN, bool HAS_BLO>
__device__ __forceinline__ f32x4 dotct(const bf16x8* ah, const bf16x8* al,
                                       const ushort* __restrict__ Bfh,
                                       const ushort* __restrict__ Bfl,
                                       int ct, int L){
  constexpr int KS = KK / 32, CT = NN / 16;
  f32x4 acc = {0.f, 0.f, 0.f, 0.f};
  #pragma unroll
  for (int ks = 0; ks < KS; ks++){
    int bo = ((ks * CT + ct) * 64 + L) * 8;
    bf16x8 bh = *(const bf16x8*)(Bfh + bo);
    acc = MFMA16(ah[ks], bh, acc);
    acc = MFMA16(al[ks], bh, acc);
    if constexpr (HAS_BLO){
      bf16x8 bl = *(const bf16x8*)(Bfl + bo);
      acc = MFMA16(ah[ks], bl, acc);
    }
  }
  return acc;
}

// ---------------- per-book: codebook -> bf16 MFMA B-fragment layout + half-norms ----------
__device__ __forceinline__ void ebook_body(const float* __restrict__ Ef, ushort* __restrict__ Eb,
                                           float* __restrict__ hen, int code, int L){
  float2 e2 = *(const float2*)(Ef + code * 128 + L * 2);
  ushort h0 = f2b_rne(e2.x), h1 = f2b_rne(e2.y);
  int d = L * 2;
  int o = ((((code >> 4) * 4 + (d >> 5)) * 4 + ((d >> 3) & 3)) * 16 + (code & 15)) * 8 + (d & 7);
  *(unsigned*)(Eb + o) = (unsigned)h0 | ((unsigned)h1 << 16);
  float eh0 = b2f(h0), eh1 = b2f(h1);
  float s = eh0 * eh0 + eh1 * eh1;
  #pragma unroll
  for (int mask = 1; mask <= 32; mask <<= 1) s += __shfl_xor(s, mask);
  if (L == 0) hen[code] = 0.5f * s;
}

// ---------------- prep: weight swizzle + BN fold + ebook(book 0) --------------------------
__device__ __forceinline__ void swz_body(const float* __restrict__ Wm, ushort* __restrict__ Wfh,
                                         ushort* __restrict__ Wfl, int N, int b){
  int gid = b * 256 + threadIdx.x;
  int k = gid / N, n = gid - k * N;
  int kt = k >> 5, kr = k & 31, nt = n >> 4, nr = n & 15;
  int lane = (kr >> 3) * 16 + nr, tt = kr & 7;
  int o = (((kt * (N >> 4)) + nt) * 64 + lane) * 8 + tt;
  float v = Wm[gid];
  ushort h = f2b_rne(v);
  Wfh[o] = h;
  if (Wfl) Wfl[o] = f2b_rne(v - b2f(h));
}

__global__ __launch_bounds__(256) void k_prep(
    const float* __restrict__ W1, const float* __restrict__ W2, const float* __restrict__ W3,
    const float* __restrict__ W4, const float* __restrict__ W5, const float* __restrict__ W6,
    ushort* W1fh, ushort* W1fl, ushort* W2fh, ushort* W2fl, ushort* W3fh, ushort* W3fl,
    ushort* W4fh, ushort* W5fh, ushort* W6fh,
    const float* __restrict__ CB, ushort* __restrict__ Eb, float* __restrict__ hen,
    const float* g1,const float* be1,const float* rm1,const float* rv1,
    const float* g2,const float* be2,const float* rm2,const float* rv2,
    const float* g3,const float* be3,const float* rm3,const float* rv3,
    const float* g4,const float* be4,const float* rm4,const float* rv4,
    float* s1,float* t1,float* s2,float* t2,float* s3,float* t3,float* s4,float* t4)
{
  int b = blockIdx.x;
  if (b < 768){
    if      (b < 128) swz_body(W1, W1fh, W1fl, 128, b);
    else if (b < 256) swz_body(W2, W2fh, W2fl, 256, b - 128);
    else if (b < 384) swz_body(W3, W3fh, W3fl, 128, b - 256);
    else if (b < 512) swz_body(W4, W4fh, nullptr, 256, b - 384);
    else if (b < 640) swz_body(W5, W5fh, nullptr, 128, b - 512);
    else              swz_body(W6, W6fh, nullptr, 256, b - 640);
  } else if (b == 768){
    int t = threadIdx.x;
    if (t < 128){
      float sa = g1[t] / sqrtf(rv1[t] + 1e-5f);
      s1[t] = sa; t1[t] = be1[t] - rm1[t] * sa;
      float sb = g4[t] / sqrtf(rv4[t] + 1e-5f);
      s4[t] = sb; t4[t] = be4[t] - rm4[t] * sb;
    }
    if (t < 256){
      float sa = g2[t] / sqrtf(rv2[t] + 1e-5f);
      s2[t] = sa; t2[t] = be2[t] - rm2[t] * sa;
      float sb = g3[t] / sqrtf(rv3[t] + 1e-5f);
      s3[t] = sb; t3[t] = be3[t] - rm3[t] * sb;
    }
  } else {
    // ebook for book 0: blocks 769..2816, 4 codes/block
    ebook_body(CB, Eb, hen, (b - 769) * 4 + (threadIdx.x >> 6), threadIdx.x & 63);
  }
}

// ---------------- fused encoder -----------------------------------------------------------
__global__ __launch_bounds__(256) void k_encoder(
    const float* __restrict__ x,
    const ushort* __restrict__ W1fh, const ushort* __restrict__ W1fl,
    const ushort* __restrict__ W2fh, const ushort* __restrict__ W2fl,
    const ushort* __restrict__ W3fh, const ushort* __restrict__ W3fl,
    const float* __restrict__ b1, const float* __restrict__ s1, const float* __restrict__ t1,
    const float* __restrict__ b2, const float* __restrict__ s2, const float* __restrict__ t2,
    const float* __restrict__ b3,
    ushort* __restrict__ rhi, float* __restrict__ res)
{
  __shared__ __align__(16) float sA[16 * 260];
  __shared__ __align__(16) float sB[16 * 132];
  int tid = threadIdx.x;
  int wv = tid >> 6, L = tid & 63;
  int qd = L >> 4, c16 = L & 15;
  int row0 = blockIdx.x * 16;

  bf16x8 a1h[8], a1l[8];
  #pragma unroll
  for (int ks = 0; ks < 8; ks++)
    cvt8(x + (row0 + c16) * 256 + ks * 32 + qd * 8, a1h[ks], a1l[ks]);

  #pragma unroll
  for (int u = 0; u < 2; u++){
    int ct = wv * 2 + u;
    f32x4 acc = dotct<256,128,true>(a1h, a1l, W1fh, W1fl, ct, L);
    int col = ct * 16 + c16;
    float bia = b1[col], sc = s1[col], sh = t1[col];
    #pragma unroll
    for (int i = 0; i < 4; i++){
      float v = (acc[i] + bia) * sc + sh;
      sB[(qd * 4 + i) * 132 + col] = fmaxf(v, 0.f);
    }
  }
  __syncthreads();

  bf16x8 a2h[4], a2l[4];
  #pragma unroll
  for (int ks = 0; ks < 4; ks++)
    cvt8(sB + c16 * 132 + ks * 32 + qd * 8, a2h[ks], a2l[ks]);

  #pragma unroll
  for (int u = 0; u < 4; u++){
    int ct = wv * 4 + u;
    f32x4 acc = dotct<128,256,true>(a2h, a2l, W2fh, W2fl, ct, L);
    int col = ct * 16 + c16;
    float bia = b2[col], sc = s2[col], sh = t2[col];
    #pragma unroll
    for (int i = 0; i < 4; i++){
      float v = (acc[i] + bia) * sc + sh;
      sA[(qd * 4 + i) * 260 + col] = fmaxf(v, 0.f);
    }
  }
  __syncthreads();

  bf16x8 a3h[8], a3l[8];
  #pragma unroll
  for (int ks = 0; ks < 8; ks++)
    cvt8(sA + c16 * 260 + ks * 32 + qd * 8, a3h[ks], a3l[ks]);

  #pragma unroll
  for (int u = 0; u < 2; u++){
    int ct = wv * 2 + u;
    f32x4 acc = dotct<256,128,true>(a3h, a3l, W3fh, W3fl, ct, L);
    int col = ct * 16 + c16;
    float bia = b3[col];
    #pragma unroll
    for (int i = 0; i < 4; i++){
      int row = row0 + qd * 4 + i;
      float v = acc[i] + bia;
      int o = row * 128 + col;
      res[o] = v;
      rhi[o] = f2b_rne(v);
    }
  }
}

// ---------------- fused decoder -----------------------------------------------------------
__global__ __launch_bounds__(256) void k_decoder(
    const ushort* __restrict__ dhi, const ushort* __restrict__ dlo,
    const ushort* __restrict__ W4fh, const ushort* __restrict__ W5fh,
    const ushort* __restrict__ W6fh,
    const float* __restrict__ b4, const float* __restrict__ s3, const float* __restrict__ t3,
    const float* __restrict__ b5, const float* __restrict__ s4, const float* __restrict__ t4,
    const float* __restrict__ b6,
    float* __restrict__ xhat)
{
  __shared__ __align__(16) float sA[16 * 260];
  __shared__ __align__(16) float sB[16 * 132];
  int tid = threadIdx.x;
  int wv = tid >> 6, L = tid & 63;
  int qd = L >> 4, c16 = L & 15;
  int row0 = blockIdx.x * 16;

  bf16x8 a1h[4], a1l[4];
  #pragma unroll
  for (int ks = 0; ks < 4; ks++){
    int off = (row0 + c16) * 128 + ks * 32 + qd * 8;
    a1h[ks] = *(const bf16x8*)(dhi + off);
    a1l[ks] = *(const bf16x8*)(dlo + off);
  }

  #pragma unroll
  for (int u = 0; u < 4; u++){
    int ct = wv * 4 + u;
    f32x4 acc = dotct<128,256,false>(a1h, a1l, W4fh, nullptr, ct, L);
    int col = ct * 16 + c16;
    float bia = b4[col], sc = s3[col], sh = t3[col];
    #pragma unroll
    for (int i = 0; i < 4; i++){
      float v = (acc[i] + bia) * sc + sh;
      sA[(qd * 4 + i) * 260 + col] = fmaxf(v, 0.f);
    }
  }
  __syncthreads();

  bf16x8 a2h[8], a2l[8];
  #pragma unroll
  for (int ks = 0; ks < 8; ks++)
    cvt8(sA + c16 * 260 + ks * 32 + qd * 8, a2h[ks], a2l[ks]);

  #pragma unroll
  for (int u = 0; u < 2; u++){
    int ct = wv * 2 + u;
    f32x4 acc = dotct<256,128,false>(a2h, a2l, W5fh, nullptr, ct, L);
    int col = ct * 16 + c16;
    float bia = b5[col], sc = s4[col], sh = t4[col];
    #pragma unroll
    for (int i = 0; i < 4; i++){
      float v = (acc[i] + bia) * sc + sh;
      sB[(qd * 4 + i) * 132 + col] = fmaxf(v, 0.f);
    }
  }
  __syncthreads();

  bf16x8 a3h[4], a3l[4];
  #pragma unroll
  for (int ks = 0; ks < 4; ks++)
    cvt8(sB + c16 * 132 + ks * 32 + qd * 8, a3h[ks], a3l[ks]);

  #pragma unroll
  for (int u = 0; u < 4; u++){
    int ct = wv * 4 + u;
    f32x4 acc = dotct<128,256,false>(a3h, a3l, W6fh, nullptr, ct, L);
    int col = ct * 16 + c16;
    float bia = b6[col];
    #pragma unroll
    for (int i = 0; i < 4; i++)
      xhat[(row0 + qd * 4 + i) * 256 + col] = acc[i] + bia;
  }
}

// ---------------- VQ: hi-only argmax(r.e - 0.5||e||^2), LDS async double-buffer -----------
// grid: 64 row-blocks (128 rows) x 16 chunks (512 codes) = 1024 = 4 blocks/CU exact.
// Per tile (64 codes, 16 KB): issue next-tile global loads -> compute 4 groups from
// LDS (4x ds_read_b128 + 8 MFMA + 8 cmp each) -> write staged regs -> ONE barrier.
// Global B traffic: one 128 KB stage per block = 128 MB/dispatch (4x less than R11).
// ~100 VGPR, 34 KB LDS -> 4 waves/SIMD. Scan order identical to R11.
__global__ __launch_bounds__(256, 4) void k_vq_argmin(
  const ushort* __restrict__ Rhi,
  const ushort* __restrict__ Eb, const float* __restrict__ hen,
  float* __restrict__ cq, int* __restrict__ cj)
{
  __shared__ __align__(16) ushort etile[2][8192];   // 2 x 16 KB
  __shared__ float henl[512];
  int rb = blockIdx.x & 63, ch = blockIdx.x >> 6;
  int tid = threadIdx.x;
  int wv = tid >> 6, L = tid & 63;
  int qd = L >> 4, c16 = L & 15;
  int row0 = rb * 128 + wv * 32;

  // resident A: 32 rows hi-only (32 VGPRs)
  bf16x8 ah[2][4];
  #pragma unroll
  for (int t = 0; t < 2; t++){
    int r = row0 + t * 16 + c16;
    #pragma unroll
    for (int ks = 0; ks < 4; ks++)
      ah[t][ks] = *(const bf16x8*)(Rhi + r * 128 + ks * 32 + qd * 8);
  }
  henl[tid] = hen[ch * 512 + tid];
  henl[tid + 256] = hen[ch * 512 + 256 + tid];

  float best[2][4]; int bj[2][4];
  #pragma unroll
  for (int t = 0; t < 2; t++)
    #pragma unroll
    for (int i = 0; i < 4; i++){ best[t][i] = -3.0e38f; bj[t][i] = 0; }

  const ushort* ebc = Eb + (size_t)ch * 65536;      // chunk base (512 codes, frag layout)
  int jb = ch * 512 + c16;

  // stage tile 0
  {
    const ushort* src = ebc + tid * 8;
    f32x4 v0 = *(const f32x4*)(src + 0 * 2048);
    f32x4 v1 = *(const f32x4*)(src + 1 * 2048);
    f32x4 v2 = *(const f32x4*)(src + 2 * 2048);
    f32x4 v3 = *(const f32x4*)(src + 3 * 2048);
    *(f32x4*)(etile[0] + 0 * 2048 + tid * 8) = v0;
    *(f32x4*)(etile[0] + 1 * 2048 + tid * 8) = v1;
    *(f32x4*)(etile[0] + 2 * 2048 + tid * 8) = v2;
    *(f32x4*)(etile[0] + 3 * 2048 + tid * 8) = v3;
  }
  __syncthreads();

  #pragma unroll 1
  for (int tile = 0; tile < 8; ++tile){
    int cur = tile & 1;
    // T14 issue-early: global loads for tile+1 (latency hides under compute below)
    f32x4 v0, v1, v2, v3;
    if (tile < 7){
      const ushort* src = ebc + (tile + 1) * 8192 + tid * 8;
      v0 = *(const f32x4*)(src + 0 * 2048);
      v1 = *(const f32x4*)(src + 1 * 2048);
      v2 = *(const f32x4*)(src + 2 * 2048);
      v3 = *(const f32x4*)(src + 3 * 2048);
    }
    // compute 4 groups of the current tile from LDS
    const ushort* lb = etile[cur];
    #pragma unroll
    for (int g = 0; g < 4; ++g){
      const ushort* gp = lb + g * 2048 + L * 8;
      bf16x8 b0 = *(const bf16x8*)(gp + 0);
      bf16x8 b1 = *(const bf16x8*)(gp + 512);
      bf16x8 b2 = *(const bf16x8*)(gp + 1024);
      bf16x8 b3 = *(const bf16x8*)(gp + 1536);
      int gg = tile * 4 + g;
      float mh = -henl[gg * 16 + c16];
      f32x4 a0 = {mh, mh, mh, mh}, a1 = {mh, mh, mh, mh};
      __builtin_amdgcn_s_setprio(1);
      a0 = MFMA16(ah[0][0], b0, a0); a1 = MFMA16(ah[1][0], b0, a1);
      a0 = MFMA16(ah[0][1], b1, a0); a1 = MFMA16(ah[1][1], b1, a1);
      a0 = MFMA16(ah[0][2], b2, a0); a1 = MFMA16(ah[1][2], b2, a1);
      a0 = MFMA16(ah[0][3], b3, a0); a1 = MFMA16(ah[1][3], b3, a1);
      __builtin_amdgcn_s_setprio(0);
      int jc = jb + gg * 16;
      #pragma unroll
      for (int i = 0; i < 4; i++){
        if (a0[i] > best[0][i]){ best[0][i] = a0[i]; bj[0][i] = jc; }
        if (a1[i] > best[1][i]){ best[1][i] = a1[i]; bj[1][i] = jc; }
      }
    }
    // T14 write-late: staged regs -> other buffer (waits vmcnt here, after compute)
    if (tile < 7){
      ushort* nb = etile[cur ^ 1];
      *(f32x4*)(nb + 0 * 2048 + tid * 8) = v0;
      *(f32x4*)(nb + 1 * 2048 + tid * 8) = v1;
      *(f32x4*)(nb + 2 * 2048 + tid * 8) = v2;
      *(f32x4*)(nb + 3 * 2048 + tid * 8) = v3;
    }
    __syncthreads();
  }

  // cross-lane reduce over the 16 code-columns, ties -> smaller j
  #pragma unroll
  for (int mask = 1; mask <= 8; mask <<= 1){
    #pragma unroll
    for (int t = 0; t < 2; t++)
      #pragma unroll
      for (int i = 0; i < 4; i++){
        float ob = __shfl_xor(best[t][i], mask);
        int   oj = __shfl_xor(bj[t][i], mask);
        if (ob > best[t][i] || (ob == best[t][i] && oj < bj[t][i])){ best[t][i] = ob; bj[t][i] = oj; }
      }
  }
  if (c16 == 0){
    #pragma unroll
    for (int t = 0; t < 2; t++)
      #pragma unroll
      for (int i = 0; i < 4; i++){
        int r = row0 + t * 16 + qd * 4 + i;
        cq[r * 16 + ch] = best[t][i];
        cj[r * 16 + ch] = bj[t][i];
      }
  }
}

// ---------------- VQ: combine 16 chunk candidates, emit res_s/ce_s, update, + next ebook --
template<bool LAST>
__global__ __launch_bounds__(256) void k_vq_update(
  const float* __restrict__ cq, const int* __restrict__ cj,
  const float* __restrict__ Ef, const float* __restrict__ Efn,
  ushort* __restrict__ Eb, float* __restrict__ hen,
  float* __restrict__ res, const float* __restrict__ ze_s,
  ushort* __restrict__ rhi, ushort* __restrict__ rlo,
  float* __restrict__ res_s, float* __restrict__ ce_s)
{
  int idx = blockIdx.x * 4 + (threadIdx.x >> 6);
  int L = threadIdx.x & 63;
  int c = L & 15;
  float bq = cq[idx * 16 + c]; int bi = cj[idx * 16 + c];
  #pragma unroll
  for (int mask = 1; mask <= 8; mask <<= 1){
    float ob = __shfl_xor(bq, mask);
    int   oj = __shfl_xor(bi, mask);
    if (ob > bq || (ob == bq && oj < bi)){ bq = ob; bi = oj; }
  }
  int o = idx * 128 + L * 2;
  float2 ce = *(const float2*)(Ef + bi * 128 + L * 2);   // fp32 codebook row
  float2 r2 = *(const float2*)(res + o);
  *(float2*)(res_s + o) = r2;
  *(float2*)(ce_s + o) = ce;
  float rn0 = r2.x - ce.x, rn1 = r2.y - ce.y;
  if constexpr (LAST){
    float2 z2 = *(const float2*)(ze_s + o);              // ze from res_s[0]
    float d0 = z2.x - rn0, d1 = z2.y - rn1;              // di = ze - res_final
    ushort h0 = f2b_rne(d0), h1 = f2b_rne(d1);
    *(unsigned*)(rhi + o) = (unsigned)h0 | ((unsigned)h1 << 16);
    ushort l0 = f2b_rne(d0 - b2f(h0)), l1 = f2b_rne(d1 - b2f(h1));
    *(unsigned*)(rlo + o) = (unsigned)l0 | ((unsigned)l1 << 16);
  } else {
    res[o] = rn0; res[o + 1] = rn1;
    ushort h0 = f2b_rne(rn0), h1 = f2b_rne(rn1);
    *(unsigned*)(rhi + o) = (unsigned)h0 | ((unsigned)h1 << 16);
    ebook_body(Efn, Eb, hen, idx, L);
  }
}

extern "C" void kernel_launch(void* const* d_in, const int* in_sizes, int n_in,
                              void* d_out, int out_size, void* d_ws, size_t ws_size,
                              hipStream_t stream)
{
  const float* x   = (const float*)d_in[0];
  const float* W1  = (const float*)d_in[1];
  const float* b1  = (const float*)d_in[2];
  const float* g1  = (const float*)d_in[3];
  const float* be1 = (const float*)d_in[4];
  const float* rm1 = (const float*)d_in[5];
  const float* rv1 = (const float*)d_in[6];
  const float* W2  = (const float*)d_in[7];
  const float* b2  = (const float*)d_in[8];
  const float* g2  = (const float*)d_in[9];
  const float* be2 = (const float*)d_in[10];
  const float* rm2 = (const float*)d_in[11];
  const float* rv2 = (const float*)d_in[12];
  const float* W3  = (const float*)d_in[13];
  const float* b3  = (const float*)d_in[14];
  const float* CB  = (const float*)d_in[15];
  const float* W4  = (const float*)d_in[16];
  const float* b4  = (const float*)d_in[17];
  const float* g3  = (const float*)d_in[18];
  const float* be3 = (const float*)d_in[19];
  const float* rm3 = (const float*)d_in[20];
  const float* rv3 = (const float*)d_in[21];
  const float* W5  = (const float*)d_in[22];
  const float* b5  = (const float*)d_in[23];
  const float* g4  = (const float*)d_in[24];
  const float* be4 = (const float*)d_in[25];
  const float* rm4 = (const float*)d_in[26];
  const float* rv4 = (const float*)d_in[27];
  const float* W6  = (const float*)d_in[28];
  const float* b6  = (const float*)d_in[29];

  char* w = (char*)d_ws;
  ushort* Eb   = (ushort*)(w + 0);             // per-book bf16 codebook (frag layout), 2 MiB
  float*  cq   = (float*) (w + 2097152);       // 8192x16, 512 KiB
  int*    cj   = (int*)   (w + 2621440);       // 8192x16, 512 KiB
  ushort* rhi  = (ushort*)(w + 12582912);      // residual hi split, 2 MiB
  ushort* rlo  = (ushort*)(w + 14680064);      // decoder dlo, 2 MiB
  float*  res  = (float*) (w + 16777216);      // 4 MiB
  float*  hen  = (float*) (w + 25165824);      // per-book half-norms, 32 KiB
  float*  s1   = (float*) (w + 25198592);
  float*  t1   = (float*) (w + 25199104);
  float*  s2   = (float*) (w + 25199616);
  float*  t2   = (float*) (w + 25200640);
  float*  s3   = (float*) (w + 25201664);
  float*  t3   = (float*) (w + 25202688);
  float*  s4   = (float*) (w + 25203712);
  float*  t4   = (float*) (w + 25204224);
  ushort* W1fh = (ushort*)(w + 25204736);
  ushort* W2fh = (ushort*)(w + 25270272);
  ushort* W3fh = (ushort*)(w + 25335808);
  ushort* W4fh = (ushort*)(w + 25401344);
  ushort* W5fh = (ushort*)(w + 25466880);
  ushort* W6fh = (ushort*)(w + 25532416);
  ushort* W1fl = (ushort*)(w + 25597952);
  ushort* W2fl = (ushort*)(w + 25663488);
  ushort* W3fl = (ushort*)(w + 25729024);

  float* xhat  = (float*)d_out;                // [8192,256] fp32
  float* res_s = xhat + 2097152;               // [8,8192,128] fp32
  float* ce_s  = res_s + 8388608;              // [8,8192,128] fp32

  // prep: weights + BN fold + ebook(book 0)
  k_prep<<<2817, 256, 0, stream>>>(W1, W2, W3, W4, W5, W6,
                                   W1fh, W1fl, W2fh, W2fl, W3fh, W3fl,
                                   W4fh, W5fh, W6fh,
                                   CB, Eb, hen,
                                   g1,be1,rm1,rv1, g2,be2,rm2,rv2,
                                   g3,be3,rm3,rv3, g4,be4,rm4,rv4,
                                   s1,t1,s2,t2,s3,t3,s4,t4);

  k_encoder<<<512, 256, 0, stream>>>(x, W1fh, W1fl, W2fh, W2fl, W3fh, W3fl,
                                     b1, s1, t1, b2, s2, t2, b3,
                                     rhi, res);

  // residual VQ over 8 books (ebook for book m+1 fused into update(m))
  for (int m = 0; m < 8; m++){
    const float* Ef = CB + (size_t)m * 1048576;
    k_vq_argmin<<<1024, 256, 0, stream>>>(rhi, Eb, hen, cq, cj);
    if (m < 7){
      k_vq_update<false><<<2048, 256, 0, stream>>>(cq, cj, Ef, Ef + 1048576, Eb, hen,
                                                   res, nullptr, rhi, nullptr,
                                                   res_s + (size_t)m * 1048576,
                                                   ce_s  + (size_t)m * 1048576);
    } else {
      k_vq_update<true><<<2048, 256, 0, stream>>>(cq, cj, Ef, nullptr, Eb, hen,
                                                  res, res_s /*ze = res_s[0]*/, rhi, rlo,
                                                  res_s + (size_t)m * 1048576,
                                                  ce_s  + (size_t)m * 1048576);
    }
  }

  // fused decoder (rhi/rlo hold split(di) from update<LAST>)
  k_decoder<<<512, 256, 0, stream>>>(rhi, rlo, W4fh, W5fh, W6fh,
                                     b4, s3, t3, b5, s4, t4, b6, xhat);
}